// Round 3
// baseline (428.264 us; speedup 1.0000x reference)
//
#include <hip/hip_runtime.h>
#include <hip/hip_fp8.h>
#include <stdint.h>

typedef unsigned short u16;
typedef unsigned char u8;
typedef __bf16 bf16x8 __attribute__((ext_vector_type(8)));
typedef float f32x4 __attribute__((ext_vector_type(4)));

__device__ __forceinline__ u16 f2bf(float f) {
  union { float f; unsigned u; } v; v.f = f;
  return (u16)((v.u + 0x7FFFu + ((v.u >> 16) & 1u)) >> 16);
}
__device__ __forceinline__ u8 f2f8(float f) {
  __hip_fp8_e4m3 h(f);
  return (u8)h.__x;
}

// async 16B global -> LDS (wave-uniform LDS base; HW writes base + lane*16)
__device__ __forceinline__ void gld_lds16(const void* g, void* l) {
  uint32_t lo = (uint32_t)(uintptr_t)l;
  lo = __builtin_amdgcn_readfirstlane(lo);
  auto* lp = (__attribute__((address_space(3))) uint32_t*)(uintptr_t)lo;
  auto* gp = (const __attribute__((address_space(1))) uint32_t*)(uintptr_t)g;
  __builtin_amdgcn_global_load_lds(gp, lp, 16, 0, 0);
}

// ---------------- weight fp32 -> bf16 ----------------
__global__ __launch_bounds__(256) void cvt_weights(
    const float* __restrict__ wq, const float* __restrict__ wp,
    u16* __restrict__ oq, u16* __restrict__ op) {
  int i = blockIdx.x * 256 + threadIdx.x;
  if (i < 1536 * 512) oq[i] = f2bf(wq[i]);
  if (i < 512 * 512)  op[i] = f2bf(wp[i]);
}

// ---------------- group norm stats ----------------
__global__ __launch_bounds__(256) void gn_stats(const float* __restrict__ x,
                                                float* __restrict__ stats) {
  int bg = blockIdx.x;  // 0..127
  const float* p = x + (size_t)bg * 65536;
  float s = 0.f, sq = 0.f;
  for (int i = threadIdx.x * 4; i < 65536; i += 1024) {
    float4 v = *(const float4*)(p + i);
    s += v.x + v.y + v.z + v.w;
    sq += v.x * v.x + v.y * v.y + v.z * v.z + v.w * v.w;
  }
  int lane = threadIdx.x & 63, w = threadIdx.x >> 6;
  for (int off = 32; off; off >>= 1) {
    s += __shfl_down(s, off);
    sq += __shfl_down(sq, off);
  }
  __shared__ float ls[4], lq[4];
  if (lane == 0) { ls[w] = s; lq[w] = sq; }
  __syncthreads();
  if (threadIdx.x == 0) {
    float S = ls[0] + ls[1] + ls[2] + ls[3];
    float Q = lq[0] + lq[1] + lq[2] + lq[3];
    float mean = S * (1.f / 65536.f);
    float var = Q * (1.f / 65536.f) - mean * mean;
    stats[bg * 2] = mean;
    stats[bg * 2 + 1] = rsqrtf(var + 1e-6f);
  }
}

// ---------------- group norm + transpose: x[b][c][n] -> xnT[b][n][c] bf16 ----
__global__ __launch_bounds__(256) void gn_norm_t(const float* __restrict__ x,
    const float* __restrict__ stats, const float* __restrict__ gamma,
    const float* __restrict__ beta, u16* __restrict__ xnT) {
  __shared__ u16 tile[64][72];
  int b = blockIdx.z;
  int c0 = blockIdx.y * 64, n0 = blockIdx.x * 64;
  int t = threadIdx.x;
  int cl = t >> 2, ng = (t & 3) * 16;
  int c = c0 + cl;
  float mean = stats[(b * 32 + (c >> 4)) * 2];
  float rstd = stats[(b * 32 + (c >> 4)) * 2 + 1];
  float a = gamma[c] * rstd;
  float b2 = beta[c] - mean * a;
  const float* src = x + ((size_t)b * 512 + c) * 4096 + n0 + ng;
  u16 e[16];
  #pragma unroll
  for (int q = 0; q < 4; ++q) {
    float4 v = *(const float4*)(src + q * 4);
    e[q * 4 + 0] = f2bf(v.x * a + b2);
    e[q * 4 + 1] = f2bf(v.y * a + b2);
    e[q * 4 + 2] = f2bf(v.z * a + b2);
    e[q * 4 + 3] = f2bf(v.w * a + b2);
  }
  #pragma unroll
  for (int j = 0; j < 16; ++j) tile[ng + j][cl] = e[j];
  __syncthreads();
  int nl = t >> 2, cg = (t & 3) * 16;
  uint4 w0 = *(const uint4*)&tile[nl][cg];
  uint4 w1 = *(const uint4*)&tile[nl][cg + 8];
  u16* dst = xnT + ((size_t)b * 4096 + n0 + nl) * 512 + c0 + cg;
  *(uint4*)dst = w0;
  *(uint4*)(dst + 8) = w1;
}

// ------------- bf16 NT GEMM: C[m][n] = sum_k A[m*lda+k]*B[n*ldb+k] --------
// 128x128 tile, BK=32, dbuf LDS + global_load_lds.
// EPI: 3 = fp32 out + bias[m] + resid (proj)
//      4 = fp8 out, (acc+bias[n])*scale  (qk: m=spatial, n=channel)
//      5 = fp8 out, acc+bias[m]          (v:  m=channel, n=spatial)
template<int EPI>
__global__ __launch_bounds__(256) void gemm_nt(
    const u16* __restrict__ A, const u16* __restrict__ B,
    int lda, int ldb, int K,
    const float* __restrict__ bias, const float* __restrict__ resid,
    float scale, float* __restrict__ outF, void* __restrict__ outBv, int ldo,
    size_t azs, size_t bzs, size_t ozs) {
  // stages (u16 idx): A0 [0,4096) A1 [4096,8192) B0 [8192,12288) B1 [12288,16384)
  // fp8 epilogue bounce: u8 128x144 overlays [0,18432) bytes
  __shared__ __align__(16) u16 smem[16384];
  const size_t z = blockIdx.z;
  A += z * azs; B += z * bzs;
  const int t = threadIdx.x;
  const int wave = t >> 6, lane = t & 63;
  const int wm = wave >> 1, wn = wave & 1;
  const int quad = lane >> 4, li = lane & 15;
  const int m0 = blockIdx.y * 128, n0 = blockIdx.x * 128;

  const int srow = lane >> 2;
  const int scol = (lane & 3) * 8;
  const u16* gA[2];
  const u16* gB[2];
  int ldsOff[2];
  #pragma unroll
  for (int r = 0; r < 2; ++r) {
    int rb = wave + 4 * r;
    gA[r] = A + (size_t)(m0 + rb * 16 + srow) * lda + scol;
    gB[r] = B + (size_t)(n0 + rb * 16 + srow) * ldb + scol;
    ldsOff[r] = rb * 512;
  }

  f32x4 zero = {0.f, 0.f, 0.f, 0.f};
  f32x4 acc[4][4];
  #pragma unroll
  for (int i = 0; i < 4; ++i)
    #pragma unroll
    for (int j = 0; j < 4; ++j) acc[i][j] = zero;

  #pragma unroll
  for (int r = 0; r < 2; ++r) {
    gld_lds16(gA[r], &smem[ldsOff[r]]);
    gld_lds16(gB[r], &smem[8192 + ldsOff[r]]);
  }
  __syncthreads();

  for (int kt = 0; kt < K; kt += 32) {
    const int s = (kt >> 5) & 1;
    if (kt + 32 < K) {
      const int ns = s ^ 1;
      #pragma unroll
      for (int r = 0; r < 2; ++r) {
        gld_lds16(gA[r] + kt + 32, &smem[ns * 4096 + ldsOff[r]]);
        gld_lds16(gB[r] + kt + 32, &smem[8192 + ns * 4096 + ldsOff[r]]);
      }
    }
    bf16x8 af[4], bf[4];
    #pragma unroll
    for (int i = 0; i < 4; ++i) {
      af[i] = *(const bf16x8*)&smem[s * 4096 +
               (wm * 64 + i * 16 + li) * 32 + quad * 8];
      bf[i] = *(const bf16x8*)&smem[8192 + s * 4096 +
               (wn * 64 + i * 16 + li) * 32 + quad * 8];
    }
    #pragma unroll
    for (int i = 0; i < 4; ++i)
      #pragma unroll
      for (int j = 0; j < 4; ++j)
        acc[i][j] = __builtin_amdgcn_mfma_f32_16x16x32_bf16(
            af[i], bf[j], acc[i][j], 0, 0, 0);
    __syncthreads();
  }

  if (EPI == 3) {
    outF += z * ozs; resid += z * ozs;
    #pragma unroll
    for (int i = 0; i < 4; ++i)
      #pragma unroll
      for (int j = 0; j < 4; ++j) {
        int mB = m0 + wm * 64 + i * 16 + quad * 4;
        int n = n0 + wn * 64 + j * 16 + li;
        #pragma unroll
        for (int r = 0; r < 4; ++r) {
          int m = mB + r;
          float v = acc[i][j][r] + bias[m] + resid[(size_t)m * ldo + n];
          outF[(size_t)m * ldo + n] = v;
        }
      }
    return;
  }

  // fp8 outputs (EPI 4/5): bounce through LDS, coalesced stores
  u8* out8 = (u8*)outBv + z * ozs;
  u8* bnc = (u8*)smem;
  #pragma unroll
  for (int i = 0; i < 4; ++i) {
    int lm = wm * 64 + i * 16 + quad * 4;
    #pragma unroll
    for (int j = 0; j < 4; ++j) {
      int ln = wn * 64 + j * 16 + li;
      #pragma unroll
      for (int r = 0; r < 4; ++r) {
        float v = acc[i][j][r];
        u8 o;
        if (EPI == 4) o = f2f8((v + bias[n0 + ln]) * scale);
        else          o = f2f8(v + bias[m0 + lm + r]);
        bnc[(lm + r) * 144 + ln] = o;
      }
    }
  }
  __syncthreads();
  {
    int row = t >> 1, half = t & 1;
    const u8* src = &bnc[row * 144 + half * 64];
    u8* dst = out8 + (size_t)(m0 + row) * ldo + n0 + half * 64;
    #pragma unroll
    for (int cc = 0; cc < 4; ++cc)
      *(uint4*)(dst + cc * 16) = *(const uint4*)(src + cc * 16);
  }
}

// ------------- fp8 NT GEMM: C[m][n] = sum_k A[m*lda+k]*B[n*ldb+k] ---------
// 128x128 tile, BK=32/stage, 3-stage LDS pipeline (prefetch distance 2) with
// counted s_waitcnt vmcnt(2) at iteration boundaries + raw s_barrier.
// Frag reads are swizzle-mapped (2-way max conflict); swizzle achieved by
// pre-swizzling the GLOBAL source address per lane (LDS dest stays linear).
// EPI: 6 = bf16 out, acc * rcp(rowsum[m])  (PV)
template<int EPI, int SWZ>
__global__ __launch_bounds__(256) void gemm_nt8(
    const u8* __restrict__ A, const u8* __restrict__ B,
    int lda, int ldb, int K,
    const float* __restrict__ rsum, float* __restrict__ outF,
    void* __restrict__ outBv, int ldo,
    size_t azs, size_t bzs, size_t ozs) {
  // stages (bytes): A s*4096 in [0,12288), B 12288+s*4096 in [12288,24576)
  // bounce overlay: EPI6 u16 128x136 = 34816
  __shared__ __align__(16) u8 smem[(EPI == 6) ? 34816 : 24576];
  const size_t z = blockIdx.z;
  A += z * azs; B += z * bzs;
  int bx = blockIdx.x, by = blockIdx.y;
  if (SWZ) {  // 16x16 super-tiles over a 32x32 grid
    int lin = by * 32 + bx;
    int tt = lin >> 8, w = lin & 255;
    by = (tt >> 1) * 16 + (w >> 4);
    bx = (tt & 1) * 16 + (w & 15);
  }
  const int t = threadIdx.x;
  const int wave = t >> 6, lane = t & 63;
  const int wm = wave >> 1, wn = wave & 1;
  const int quad = lane >> 4, li = lane & 15;
  const int m0 = by * 128, n0 = bx * 128;

  // staging: pre-swizzled source.  u = l ^ ((l>>3)&7); row = u>>1, half = u&1.
  const int us = lane ^ ((lane >> 3) & 7);
  const int srow = (us >> 1) & 31;
  const int shalf = us & 1;
  const u8* gA = A + (size_t)(m0 + wave * 32 + srow) * lda + shalf * 16;
  const u8* gB = B + (size_t)(n0 + wave * 32 + srow) * ldb + shalf * 16;
  const int ldsOff = wave * 1024;

  // frag read offsets: p = (2*r5+h) ^ ((r5>>2)&7)
  const int h = quad >> 1, qlo = (quad & 1) * 8;
  int aoff[4], boff[4];
  #pragma unroll
  for (int i = 0; i < 4; ++i) {
    int r5 = (i & 1) * 16 + li;
    int p = (2 * r5 + h) ^ ((r5 >> 2) & 7);
    aoff[i] = (wm * 2 + (i >> 1)) * 1024 + p * 16 + qlo;
    boff[i] = (wn * 2 + (i >> 1)) * 1024 + p * 16 + qlo;
  }

  f32x4 zero = {0.f, 0.f, 0.f, 0.f};
  f32x4 acc[4][4];
  #pragma unroll
  for (int i = 0; i < 4; ++i)
    #pragma unroll
    for (int j = 0; j < 4; ++j) acc[i][j] = zero;

  // prologue: stage kt=0 and kt=32, wait only for kt=0 (vmcnt(2))
  gld_lds16(gA, &smem[ldsOff]);
  gld_lds16(gB, &smem[12288 + ldsOff]);
  gld_lds16(gA + 32, &smem[4096 + ldsOff]);
  gld_lds16(gB + 32, &smem[12288 + 4096 + ldsOff]);
  asm volatile("s_waitcnt vmcnt(2)" ::: "memory");
  asm volatile("s_barrier" ::: "memory");

  int s = 0;
  for (int kt = 0; kt < K; kt += 32) {
    if (kt + 64 < K) {
      const int ns = (s == 0) ? 2 : s - 1;  // (s+2)%3
      gld_lds16(gA + kt + 64, &smem[ns * 4096 + ldsOff]);
      gld_lds16(gB + kt + 64, &smem[12288 + ns * 4096 + ldsOff]);
    }
    const int sb = s * 4096;
    long af[4], bf[4];
    #pragma unroll
    for (int i = 0; i < 4; ++i) {
      af[i] = *(const long*)&smem[sb + aoff[i]];
      bf[i] = *(const long*)&smem[12288 + sb + boff[i]];
    }
    #pragma unroll
    for (int i = 0; i < 4; ++i)
      #pragma unroll
      for (int j = 0; j < 4; ++j)
        acc[i][j] = __builtin_amdgcn_mfma_f32_16x16x32_fp8_fp8(
            af[i], bf[j], acc[i][j], 0, 0, 0);
    if (kt + 32 < K) {
      if (kt + 64 < K) asm volatile("s_waitcnt vmcnt(2)" ::: "memory");
      else             asm volatile("s_waitcnt vmcnt(0)" ::: "memory");
      asm volatile("s_barrier" ::: "memory");
    }
    s = (s == 2) ? 0 : s + 1;
  }
  __syncthreads();  // all waves done reading stages before bounce overlay

  {  // EPI 6: PV
    const float* rsF = rsum + z * 4096;
    u16* outp = (u16*)outBv + z * ozs;
    u16* b16 = (u16*)smem;
    #pragma unroll
    for (int i = 0; i < 4; ++i) {
      int lm = wm * 64 + i * 16 + quad * 4;
      float rinv[4];
      #pragma unroll
      for (int r = 0; r < 4; ++r)
        rinv[r] = __builtin_amdgcn_rcpf(rsF[m0 + lm + r]);
      #pragma unroll
      for (int j = 0; j < 4; ++j) {
        int ln = wn * 64 + j * 16 + li;
        #pragma unroll
        for (int r = 0; r < 4; ++r)
          b16[(lm + r) * 136 + ln] = f2bf(acc[i][j][r] * rinv[r]);
      }
    }
    __syncthreads();
    int row = t >> 1, half = t & 1;
    const u16* src = &b16[row * 136 + half * 64];
    u16* dst = outp + (size_t)(m0 + row) * ldo + n0 + half * 64;
    #pragma unroll
    for (int cc = 0; cc < 8; ++cc)
      *(uint4*)(dst + cc * 8) = *(const uint4*)(src + cc * 8);
  }
}

// ------------- QK^T: pipelined 256x256-tile fp8 GEMM + exp + rowsum -------
// 8 waves (2x4), per-wave C = 128x64 (Mrep=8, Nrep=4), BK=64 as two BK=32
// panels. Triple-buffered LDS K-tiles (3 x 32KB), prefetch distance = 2
// tiles via global_load_lds, boundary wait = s_waitcnt vmcnt(4). 4 compute
// phases per K-tile (C-quadrants, 16 MFMA each) with raw s_barrier pairs +
// s_setprio around MFMA clusters.  STAGING IS BANK-SWIZZLED (round-2 scheme):
// within each 1KB (32-row x 32B) region, chunk p = (2*row+half)^((row>>2)&7)
// holds (row,half); achieved by pre-swizzling the per-lane GLOBAL source
// address (LDS dest stays linear for global_load_lds). Frag reads use the
// matching p — max 2-way conflicts instead of 4-way.
__global__ __launch_bounds__(512, 2) void qk8p(
    const u8* __restrict__ A, const u8* __restrict__ B,
    float* __restrict__ rowsum, u8* __restrict__ outE) {
  // buffers: buf b at b*32768; within buf: A panels k16=0/1 at k*8192,
  // B at +16384 likewise. Epilogue bounce u8 [256][272] overlays smem.
  __shared__ __align__(16) u8 smem[98304];

  // XCD-contiguous work remap over the 1024-block grid (T1, bijective)
  int gblk = (blockIdx.z * 16 + blockIdx.y) * 16 + blockIdx.x;
  int work = (gblk & 7) * 128 + (gblk >> 3);
  int z  = work >> 8;
  int wr = work & 255;
  int by = wr >> 4, bx = wr & 15;
  const int m0 = by * 256, n0 = bx * 256;
  A += (size_t)z * 4096 * 1024;
  B += (size_t)z * 4096 * 1024;
  float* rsF = rowsum + (size_t)z * 4096;
  u8* outp = outE + (size_t)z * 4096 * 4096;

  const int t = threadIdx.x;
  const int lane = t & 63, w = t >> 6;
  const int wm = w >> 2, wn = w & 3;       // wave grid 2 (M) x 4 (N)
  const int quad = lane >> 4, li = lane & 15;

  // staging (pre-swizzled global source, linear LDS dest):
  // u = lane ^ ((lane>>3)&7); srow = u>>1 (0..31), shalf = u&1.
  const int us = lane ^ ((lane >> 3) & 7);
  const int srow = (us >> 1) & 31;
  const int shalf = us & 1;
  const u8* gA[2];
  const u8* gB[2];
  uint32_t lA[2], lB[2];
  #pragma unroll
  for (int g = 0; g < 2; ++g) {
    gA[g] = A + (size_t)(m0 + w * 32 + srow) * 1024 + g * 32 + shalf * 16;
    gB[g] = B + (size_t)(n0 + w * 32 + srow) * 1024 + g * 32 + shalf * 16;
    lA[g] = g * 8192 + w * 1024;
    lB[g] = 16384 + g * 8192 + w * 1024;
  }

  // frag read offsets (within a panel): region*1024 + p*16 + qlo,
  // p = (2*r5+h)^((r5>>2)&7), h = quad>>1, qlo = (quad&1)*8.
  const int h = quad >> 1, qlo = (quad & 1) * 8;
  int pa[4], pb[2];
  #pragma unroll
  for (int i = 0; i < 4; ++i) {
    int r5 = (i & 1) * 16 + li;
    int p = (2 * r5 + h) ^ ((r5 >> 2) & 7);
    pa[i] = (i >> 1) * 1024 + p * 16 + qlo;
  }
  #pragma unroll
  for (int j = 0; j < 2; ++j) {
    int r5 = j * 16 + li;
    int p = (2 * r5 + h) ^ ((r5 >> 2) & 7);
    pb[j] = p * 16 + qlo;
  }
  const uint32_t aB0 = (uint32_t)wm * 4096;          // + ihalf*2048 + pa[i]
  const uint32_t bB0 = 16384 + (uint32_t)wn * 2048;  // + jhalf*1024 + pb[j]

  f32x4 zero = {0.f, 0.f, 0.f, 0.f};
  f32x4 acc[8][4];
  #pragma unroll
  for (int i = 0; i < 8; ++i)
    #pragma unroll
    for (int j = 0; j < 4; ++j) acc[i][j] = zero;

  // prologue: stage tiles 0 and 1 (issue order fixed: A0,B0,A1,B1 per tile)
  #pragma unroll
  for (int tt = 0; tt < 2; ++tt) {
    gld_lds16(gA[0] + tt * 64, &smem[tt * 32768 + lA[0]]);
    gld_lds16(gB[0] + tt * 64, &smem[tt * 32768 + lB[0]]);
    gld_lds16(gA[1] + tt * 64, &smem[tt * 32768 + lA[1]]);
    gld_lds16(gB[1] + tt * 64, &smem[tt * 32768 + lB[1]]);
  }
  asm volatile("s_waitcnt vmcnt(4)" ::: "memory");  // tile0 landed
  asm volatile("s_barrier" ::: "memory");

  uint32_t bo = 0, bp = 65536;
  #pragma unroll 1
  for (int tt = 0; tt < 8; ++tt) {
    const bool pf = tt < 6;            // prefetch tile tt+2 exists
    const int kp = tt * 64 + 128;      // its K offset
    long a[8], b0[4], b1[4];

    // ---- phase 0: read A-half0 + B-half0, prefetch A panel0 ----
    #pragma unroll
    for (int i = 0; i < 4; ++i)
      #pragma unroll
      for (int k = 0; k < 2; ++k)
        a[i * 2 + k] = *(const long*)&smem[bo + k * 8192 + aB0 + pa[i]];
    #pragma unroll
    for (int j = 0; j < 2; ++j)
      #pragma unroll
      for (int k = 0; k < 2; ++k)
        b0[j * 2 + k] = *(const long*)&smem[bo + k * 8192 + bB0 + pb[j]];
    if (pf) gld_lds16(gA[0] + kp, &smem[bp + lA[0]]);
    asm volatile("s_barrier" ::: "memory");
    __builtin_amdgcn_s_setprio(1);
    #pragma unroll
    for (int i = 0; i < 4; ++i)
      #pragma unroll
      for (int j = 0; j < 2; ++j) {
        acc[i][j] = __builtin_amdgcn_mfma_f32_16x16x32_fp8_fp8(
            a[i * 2 + 0], b0[j * 2 + 0], acc[i][j], 0, 0, 0);
        acc[i][j] = __builtin_amdgcn_mfma_f32_16x16x32_fp8_fp8(
            a[i * 2 + 1], b0[j * 2 + 1], acc[i][j], 0, 0, 0);
      }
    __builtin_amdgcn_s_setprio(0);
    asm volatile("s_barrier" ::: "memory");

    // ---- phase 1: read B-half1, prefetch B panel0 ----
    #pragma unroll
    for (int j = 0; j < 2; ++j)
      #pragma unroll
      for (int k = 0; k < 2; ++k)
        b1[j * 2 + k] =
            *(const long*)&smem[bo + k * 8192 + bB0 + 1024 + pb[j]];
    if (pf) gld_lds16(gB[0] + kp, &smem[bp + lB[0]]);
    asm volatile("s_barrier" ::: "memory");
    __builtin_amdgcn_s_setprio(1);
    #pragma unroll
    for (int i = 0; i < 4; ++i)
      #pragma unroll
      for (int j = 0; j < 2; ++j) {
        acc[i][2 + j] = __builtin_amdgcn_mfma_f32_16x16x32_fp8_fp8(
            a[i * 2 + 0], b1[j * 2 + 0], acc[i][2 + j], 0, 0, 0);
        acc[i][2 + j] = __builtin_amdgcn_mfma_f32_16x16x32_fp8_fp8(
            a[i * 2 + 1], b1[j * 2 + 1], acc[i][2 + j], 0, 0, 0);
      }
    __builtin_amdgcn_s_setprio(0);
    asm volatile("s_barrier" ::: "memory");

    // ---- phase 2: read A-half1 (reuse a[]), prefetch A panel1 ----
    #pragma unroll
    for (int i = 0; i < 4; ++i)
      #pragma unroll
      for (int k = 0; k < 2; ++k)
        a[i * 2 + k] =
            *(const long*)&smem[bo + k * 8192 + aB0 + 2048 + pa[i]];
    if (pf) gld_lds16(gA[1] + kp, &smem[bp + lA[1]]);
    asm volatile("s_barrier" ::: "memory");
    __builtin_amdgcn_s_setprio(1);
    #pragma unroll
    for (int i = 0; i < 4; ++i)
      #pragma unroll
      for (int j = 0; j < 2; ++j) {
        acc[4 + i][2 + j] = __builtin_amdgcn_mfma_f32_16x16x32_fp8_fp8(
            a[i * 2 + 0], b1[j * 2 + 0], acc[4 + i][2 + j], 0, 0, 0);
        acc[4 + i][2 + j] = __builtin_amdgcn_mfma_f32_16x16x32_fp8_fp8(
            a[i * 2 + 1], b1[j * 2 + 1], acc[4 + i][2 + j], 0, 0, 0);
      }
    __builtin_amdgcn_s_setprio(0);
    asm volatile("s_barrier" ::: "memory");

    // ---- phase 3: no reads (A1,B0 live), prefetch B panel1, boundary ----
    if (pf) {
      gld_lds16(gB[1] + kp, &smem[bp + lB[1]]);
      asm volatile("s_waitcnt vmcnt(4)" ::: "memory");  // tile tt+1 landed
    } else {
      asm volatile("s_waitcnt vmcnt(0)" ::: "memory");
    }
    asm volatile("s_barrier" ::: "memory");
    __builtin_amdgcn_s_setprio(1);
    #pragma unroll
    for (int i = 0; i < 4; ++i)
      #pragma unroll
      for (int j = 0; j < 2; ++j) {
        acc[4 + i][j] = __builtin_amdgcn_mfma_f32_16x16x32_fp8_fp8(
            a[i * 2 + 0], b0[j * 2 + 0], acc[4 + i][j], 0, 0, 0);
        acc[4 + i][j] = __builtin_amdgcn_mfma_f32_16x16x32_fp8_fp8(
            a[i * 2 + 1], b0[j * 2 + 1], acc[4 + i][j], 0, 0, 0);
      }
    __builtin_amdgcn_s_setprio(0);
    asm volatile("s_barrier" ::: "memory");

    bo += 32768; if (bo == 98304) bo = 0;
    bp += 32768; if (bp == 98304) bp = 0;
  }

  // ---- epilogue: exp + clamp, rowsum atomics, fp8 bounce + coalesced out --
  u8* bnc = smem;
  #pragma unroll
  for (int I = 0; I < 8; ++I) {
    int lm = wm * 128 + I * 16 + quad * 4;
    float rs[4] = {0.f, 0.f, 0.f, 0.f};
    #pragma unroll
    for (int j = 0; j < 4; ++j) {
      int ln = wn * 64 + j * 16 + li;
      #pragma unroll
      for (int r = 0; r < 4; ++r) {
        float e = fminf(__expf(acc[I][j][r]), 448.f);
        bnc[(lm + r) * 272 + ln] = f2f8(e);
        rs[r] += e;
      }
    }
    #pragma unroll
    for (int r = 0; r < 4; ++r) {
      rs[r] += __shfl_xor(rs[r], 1);
      rs[r] += __shfl_xor(rs[r], 2);
      rs[r] += __shfl_xor(rs[r], 4);
      rs[r] += __shfl_xor(rs[r], 8);
    }
    if (li == 0) {
      #pragma unroll
      for (int r = 0; r < 4; ++r) atomicAdd(&rsF[m0 + lm + r], rs[r]);
    }
  }
  __syncthreads();
  {
    int row = t >> 1, half = t & 1;
    const u8* src = &bnc[row * 272 + half * 128];
    u8* dst = outp + (size_t)(m0 + row) * 4096 + n0 + half * 128;
    #pragma unroll
    for (int cc = 0; cc < 8; ++cc)
      *(uint4*)(dst + cc * 16) = *(const uint4*)(src + cc * 16);
  }
}

extern "C" void kernel_launch(void* const* d_in, const int* in_sizes, int n_in,
                              void* d_out, int out_size, void* d_ws, size_t ws_size,
                              hipStream_t stream) {
  (void)in_sizes; (void)n_in; (void)out_size; (void)ws_size;
  const float* x      = (const float*)d_in[0];
  const float* gamma  = (const float*)d_in[1];
  const float* beta   = (const float*)d_in[2];
  const float* w_qkv  = (const float*)d_in[3];
  const float* b_qkv  = (const float*)d_in[4];
  const float* w_proj = (const float*)d_in[5];
  const float* b_proj = (const float*)d_in[6];
  float* out = (float*)d_out;

  const int C = 512, N = 4096;
  const size_t NC = (size_t)N * C;
  const float scale = 0.21022410381342863f;  // 512^-0.25

  char* ws = (char*)d_ws;
  size_t off = 0;
  auto alloc = [&](size_t bytes) -> char* {
    char* p = ws + off; off += (bytes + 255) & ~(size_t)255; return p;
  };
  u16*   wq_bf  = (u16*)alloc((size_t)1536 * 512 * 2);
  u16*   wp_bf  = (u16*)alloc((size_t)512 * 512 * 2);
  float* stats  = (float*)alloc(128 * 2 * 4);
  float* rowsum = (float*)alloc((size_t)4 * N * 4);
  u16*   xnT    = (u16*)alloc((size_t)4 * NC * 2);      // [b][n][c] bf16
  u8*    qkT    = (u8*)alloc((size_t)4 * N * 1024);     // [b][i][o] fp8, o<1024
  u8*    vbf    = (u8*)alloc((size_t)4 * 512 * 4096);   // [b][c][j] fp8
  u16*   ao     = (u16*)alloc((size_t)4 * NC * 2);      // [b][i][c] bf16
  u8*    E      = (u8*)alloc((size_t)4 * N * N);        // [b][i][j] fp8

  cvt_weights<<<3072, 256, 0, stream>>>(w_qkv, w_proj, wq_bf, wp_bf);
  gn_stats<<<128, 256, 0, stream>>>(x, stats);
  gn_norm_t<<<dim3(64, 8, 4), 256, 0, stream>>>(x, stats, gamma, beta, xnT);
  hipMemsetAsync(rowsum, 0, (size_t)4 * N * 4, stream);

  // qkT[b][i][o] = fp8((sum_c xnT[b][i][c]*wq[o][c] + b_qkv[o]) * scale)
  gemm_nt<4><<<dim3(8, 32, 4), 256, 0, stream>>>(
      xnT, wq_bf, 512, 512, 512, b_qkv, nullptr, scale,
      nullptr, qkT, 1024, NC, 0, (size_t)N * 1024);
  // vbf[b][c][j] = fp8(sum_k wq[1024+c][k]*xnT[b][j][k] + b_qkv[1024+c])
  gemm_nt<5><<<dim3(32, 4, 4), 256, 0, stream>>>(
      wq_bf + (size_t)1024 * 512, xnT, 512, 512, 512, b_qkv + 1024, nullptr,
      0.f, nullptr, vbf, 4096, 0, NC, (size_t)512 * 4096);
  // E[b][i][j] = fp8(exp(S)), rowsum[b][i] += partials (pipelined 256^2,
  // swizzled staging + frag reads)
  qk8p<<<dim3(16, 16, 4), 512, 0, stream>>>(qkT, qkT + 512, rowsum, E);
  // ao[b][i][c] = bf16((sum_j E*v) * rcp(rowsum[b][i]))  (K=4096, fp8 MFMA)
  gemm_nt8<6, 0><<<dim3(4, 32, 4), 256, 0, stream>>>(
      E, vbf, 4096, 4096, 4096, rowsum, nullptr,
      ao, 512, (size_t)N * N, (size_t)512 * 4096, NC);
  // out[b][o][n] = sum_c wp[o][c]*ao[b][n][c] + b_proj[o] + x[b][o][n]
  gemm_nt<3><<<dim3(32, 4, 4), 256, 0, stream>>>(
      wp_bf, ao, 512, 512, 512, b_proj, x, 0.f,
      out, nullptr, 4096, 0, NC, NC);
}

// Round 4
// 420.931 us; speedup vs baseline: 1.0174x; 1.0174x over previous
//
#include <hip/hip_runtime.h>
#include <hip/hip_fp8.h>
#include <stdint.h>

typedef unsigned short u16;
typedef unsigned char u8;
typedef __bf16 bf16x8 __attribute__((ext_vector_type(8)));
typedef float f32x4 __attribute__((ext_vector_type(4)));

__device__ __forceinline__ u16 f2bf(float f) {
  union { float f; unsigned u; } v; v.f = f;
  return (u16)((v.u + 0x7FFFu + ((v.u >> 16) & 1u)) >> 16);
}
__device__ __forceinline__ u8 f2f8(float f) {
  __hip_fp8_e4m3 h(f);
  return (u8)h.__x;
}

// async 16B global -> LDS (wave-uniform LDS base; HW writes base + lane*16)
__device__ __forceinline__ void gld_lds16(const void* g, void* l) {
  uint32_t lo = (uint32_t)(uintptr_t)l;
  lo = __builtin_amdgcn_readfirstlane(lo);
  auto* lp = (__attribute__((address_space(3))) uint32_t*)(uintptr_t)lo;
  auto* gp = (const __attribute__((address_space(1))) uint32_t*)(uintptr_t)g;
  __builtin_amdgcn_global_load_lds(gp, lp, 16, 0, 0);
}

// clobber-free barrier, fenced so no memory op crosses at schedule time.
// (asm "memory" clobber would make SIInsertWaitcnts emit vmcnt(0) before
// every barrier, silently draining the pipeline — the round-3 stall.)
__device__ __forceinline__ void bar() {
  __builtin_amdgcn_sched_barrier(0);
  __builtin_amdgcn_s_barrier();
  __builtin_amdgcn_sched_barrier(0);
}

// ---------------- weight fp32 -> bf16 ----------------
__global__ __launch_bounds__(256) void cvt_weights(
    const float* __restrict__ wq, const float* __restrict__ wp,
    u16* __restrict__ oq, u16* __restrict__ op) {
  int i = blockIdx.x * 256 + threadIdx.x;
  if (i < 1536 * 512) oq[i] = f2bf(wq[i]);
  if (i < 512 * 512)  op[i] = f2bf(wp[i]);
}

// ---------------- group norm stats ----------------
__global__ __launch_bounds__(256) void gn_stats(const float* __restrict__ x,
                                                float* __restrict__ stats) {
  int bg = blockIdx.x;  // 0..127
  const float* p = x + (size_t)bg * 65536;
  float s = 0.f, sq = 0.f;
  for (int i = threadIdx.x * 4; i < 65536; i += 1024) {
    float4 v = *(const float4*)(p + i);
    s += v.x + v.y + v.z + v.w;
    sq += v.x * v.x + v.y * v.y + v.z * v.z + v.w * v.w;
  }
  int lane = threadIdx.x & 63, w = threadIdx.x >> 6;
  for (int off = 32; off; off >>= 1) {
    s += __shfl_down(s, off);
    sq += __shfl_down(sq, off);
  }
  __shared__ float ls[4], lq[4];
  if (lane == 0) { ls[w] = s; lq[w] = sq; }
  __syncthreads();
  if (threadIdx.x == 0) {
    float S = ls[0] + ls[1] + ls[2] + ls[3];
    float Q = lq[0] + lq[1] + lq[2] + lq[3];
    float mean = S * (1.f / 65536.f);
    float var = Q * (1.f / 65536.f) - mean * mean;
    stats[bg * 2] = mean;
    stats[bg * 2 + 1] = rsqrtf(var + 1e-6f);
  }
}

// ---------------- group norm + transpose: x[b][c][n] -> xnT[b][n][c] bf16 ----
__global__ __launch_bounds__(256) void gn_norm_t(const float* __restrict__ x,
    const float* __restrict__ stats, const float* __restrict__ gamma,
    const float* __restrict__ beta, u16* __restrict__ xnT) {
  __shared__ u16 tile[64][72];
  int b = blockIdx.z;
  int c0 = blockIdx.y * 64, n0 = blockIdx.x * 64;
  int t = threadIdx.x;
  int cl = t >> 2, ng = (t & 3) * 16;
  int c = c0 + cl;
  float mean = stats[(b * 32 + (c >> 4)) * 2];
  float rstd = stats[(b * 32 + (c >> 4)) * 2 + 1];
  float a = gamma[c] * rstd;
  float b2 = beta[c] - mean * a;
  const float* src = x + ((size_t)b * 512 + c) * 4096 + n0 + ng;
  u16 e[16];
  #pragma unroll
  for (int q = 0; q < 4; ++q) {
    float4 v = *(const float4*)(src + q * 4);
    e[q * 4 + 0] = f2bf(v.x * a + b2);
    e[q * 4 + 1] = f2bf(v.y * a + b2);
    e[q * 4 + 2] = f2bf(v.z * a + b2);
    e[q * 4 + 3] = f2bf(v.w * a + b2);
  }
  #pragma unroll
  for (int j = 0; j < 16; ++j) tile[ng + j][cl] = e[j];
  __syncthreads();
  int nl = t >> 2, cg = (t & 3) * 16;
  uint4 w0 = *(const uint4*)&tile[nl][cg];
  uint4 w1 = *(const uint4*)&tile[nl][cg + 8];
  u16* dst = xnT + ((size_t)b * 4096 + n0 + nl) * 512 + c0 + cg;
  *(uint4*)dst = w0;
  *(uint4*)(dst + 8) = w1;
}

// ------------- bf16 NT GEMM: C[m][n] = sum_k A[m*lda+k]*B[n*ldb+k] --------
// 128x128 tile, BK=32, dbuf LDS + global_load_lds.
// EPI: 3 = fp32 out + bias[m] + resid (proj)
//      4 = fp8 out, (acc+bias[n])*scale  (qk: m=spatial, n=channel)
//      5 = fp8 out, acc+bias[m]          (v:  m=channel, n=spatial)
template<int EPI>
__global__ __launch_bounds__(256) void gemm_nt(
    const u16* __restrict__ A, const u16* __restrict__ B,
    int lda, int ldb, int K,
    const float* __restrict__ bias, const float* __restrict__ resid,
    float scale, float* __restrict__ outF, void* __restrict__ outBv, int ldo,
    size_t azs, size_t bzs, size_t ozs) {
  // stages (u16 idx): A0 [0,4096) A1 [4096,8192) B0 [8192,12288) B1 [12288,16384)
  // fp8 epilogue bounce: u8 128x144 overlays [0,18432) bytes
  __shared__ __align__(16) u16 smem[16384];
  const size_t z = blockIdx.z;
  A += z * azs; B += z * bzs;
  const int t = threadIdx.x;
  const int wave = t >> 6, lane = t & 63;
  const int wm = wave >> 1, wn = wave & 1;
  const int quad = lane >> 4, li = lane & 15;
  const int m0 = blockIdx.y * 128, n0 = blockIdx.x * 128;

  const int srow = lane >> 2;
  const int scol = (lane & 3) * 8;
  const u16* gA[2];
  const u16* gB[2];
  int ldsOff[2];
  #pragma unroll
  for (int r = 0; r < 2; ++r) {
    int rb = wave + 4 * r;
    gA[r] = A + (size_t)(m0 + rb * 16 + srow) * lda + scol;
    gB[r] = B + (size_t)(n0 + rb * 16 + srow) * ldb + scol;
    ldsOff[r] = rb * 512;
  }

  f32x4 zero = {0.f, 0.f, 0.f, 0.f};
  f32x4 acc[4][4];
  #pragma unroll
  for (int i = 0; i < 4; ++i)
    #pragma unroll
    for (int j = 0; j < 4; ++j) acc[i][j] = zero;

  #pragma unroll
  for (int r = 0; r < 2; ++r) {
    gld_lds16(gA[r], &smem[ldsOff[r]]);
    gld_lds16(gB[r], &smem[8192 + ldsOff[r]]);
  }
  __syncthreads();

  for (int kt = 0; kt < K; kt += 32) {
    const int s = (kt >> 5) & 1;
    if (kt + 32 < K) {
      const int ns = s ^ 1;
      #pragma unroll
      for (int r = 0; r < 2; ++r) {
        gld_lds16(gA[r] + kt + 32, &smem[ns * 4096 + ldsOff[r]]);
        gld_lds16(gB[r] + kt + 32, &smem[8192 + ns * 4096 + ldsOff[r]]);
      }
    }
    bf16x8 af[4], bf[4];
    #pragma unroll
    for (int i = 0; i < 4; ++i) {
      af[i] = *(const bf16x8*)&smem[s * 4096 +
               (wm * 64 + i * 16 + li) * 32 + quad * 8];
      bf[i] = *(const bf16x8*)&smem[8192 + s * 4096 +
               (wn * 64 + i * 16 + li) * 32 + quad * 8];
    }
    #pragma unroll
    for (int i = 0; i < 4; ++i)
      #pragma unroll
      for (int j = 0; j < 4; ++j)
        acc[i][j] = __builtin_amdgcn_mfma_f32_16x16x32_bf16(
            af[i], bf[j], acc[i][j], 0, 0, 0);
    __syncthreads();
  }

  if (EPI == 3) {
    outF += z * ozs; resid += z * ozs;
    #pragma unroll
    for (int i = 0; i < 4; ++i)
      #pragma unroll
      for (int j = 0; j < 4; ++j) {
        int mB = m0 + wm * 64 + i * 16 + quad * 4;
        int n = n0 + wn * 64 + j * 16 + li;
        #pragma unroll
        for (int r = 0; r < 4; ++r) {
          int m = mB + r;
          float v = acc[i][j][r] + bias[m] + resid[(size_t)m * ldo + n];
          outF[(size_t)m * ldo + n] = v;
        }
      }
    return;
  }

  // fp8 outputs (EPI 4/5): bounce through LDS, coalesced stores
  u8* out8 = (u8*)outBv + z * ozs;
  u8* bnc = (u8*)smem;
  #pragma unroll
  for (int i = 0; i < 4; ++i) {
    int lm = wm * 64 + i * 16 + quad * 4;
    #pragma unroll
    for (int j = 0; j < 4; ++j) {
      int ln = wn * 64 + j * 16 + li;
      #pragma unroll
      for (int r = 0; r < 4; ++r) {
        float v = acc[i][j][r];
        u8 o;
        if (EPI == 4) o = f2f8((v + bias[n0 + ln]) * scale);
        else          o = f2f8(v + bias[m0 + lm + r]);
        bnc[(lm + r) * 144 + ln] = o;
      }
    }
  }
  __syncthreads();
  {
    int row = t >> 1, half = t & 1;
    const u8* src = &bnc[row * 144 + half * 64];
    u8* dst = out8 + (size_t)(m0 + row) * ldo + n0 + half * 64;
    #pragma unroll
    for (int cc = 0; cc < 4; ++cc)
      *(uint4*)(dst + cc * 16) = *(const uint4*)(src + cc * 16);
  }
}

// ------------- fp8 NT GEMM: C[m][n] = sum_k A[m*lda+k]*B[n*ldb+k] ---------
// 128x128 tile, BK=32/stage, 3-stage LDS pipeline (prefetch distance 2) with
// counted s_waitcnt vmcnt(2) at iteration boundaries (CLOBBER-FREE asm +
// sched_barrier fences + builtin s_barrier; a "memory" clobber would force
// vmcnt(0) drains at every barrier).  Frag reads swizzle-mapped (2-way max
// conflict) via pre-swizzled GLOBAL source (LDS dest linear).
// EPI: 6 = bf16 out, acc * rcp(rowsum[m])  (PV)
template<int EPI, int SWZ>
__global__ __launch_bounds__(256) void gemm_nt8(
    const u8* __restrict__ A, const u8* __restrict__ B,
    int lda, int ldb, int K,
    const float* __restrict__ rsum, float* __restrict__ outF,
    void* __restrict__ outBv, int ldo,
    size_t azs, size_t bzs, size_t ozs) {
  // stages (bytes): A s*4096 in [0,12288), B 12288+s*4096 in [12288,24576)
  // bounce overlay: EPI6 u16 128x136 = 34816
  __shared__ __align__(16) u8 smem[(EPI == 6) ? 34816 : 24576];
  const size_t z = blockIdx.z;
  A += z * azs; B += z * bzs;
  int bx = blockIdx.x, by = blockIdx.y;
  if (SWZ) {  // 16x16 super-tiles over a 32x32 grid
    int lin = by * 32 + bx;
    int tt = lin >> 8, w = lin & 255;
    by = (tt >> 1) * 16 + (w >> 4);
    bx = (tt & 1) * 16 + (w & 15);
  }
  const int t = threadIdx.x;
  const int wave = t >> 6, lane = t & 63;
  const int wm = wave >> 1, wn = wave & 1;
  const int quad = lane >> 4, li = lane & 15;
  const int m0 = by * 128, n0 = bx * 128;

  // staging: pre-swizzled source.  u = l ^ ((l>>3)&7); row = u>>1, half = u&1.
  const int us = lane ^ ((lane >> 3) & 7);
  const int srow = (us >> 1) & 31;
  const int shalf = us & 1;
  const u8* gA = A + (size_t)(m0 + wave * 32 + srow) * lda + shalf * 16;
  const u8* gB = B + (size_t)(n0 + wave * 32 + srow) * ldb + shalf * 16;
  const int ldsOff = wave * 1024;

  // frag read offsets: p = (2*r5+h) ^ ((r5>>2)&7)
  const int h = quad >> 1, qlo = (quad & 1) * 8;
  int aoff[4], boff[4];
  #pragma unroll
  for (int i = 0; i < 4; ++i) {
    int r5 = (i & 1) * 16 + li;
    int p = (2 * r5 + h) ^ ((r5 >> 2) & 7);
    aoff[i] = (wm * 2 + (i >> 1)) * 1024 + p * 16 + qlo;
    boff[i] = (wn * 2 + (i >> 1)) * 1024 + p * 16 + qlo;
  }

  f32x4 zero = {0.f, 0.f, 0.f, 0.f};
  f32x4 acc[4][4];
  #pragma unroll
  for (int i = 0; i < 4; ++i)
    #pragma unroll
    for (int j = 0; j < 4; ++j) acc[i][j] = zero;

  // prologue: stage kt=0 and kt=32, wait only for kt=0 (vmcnt(2))
  gld_lds16(gA, &smem[ldsOff]);
  gld_lds16(gB, &smem[12288 + ldsOff]);
  gld_lds16(gA + 32, &smem[4096 + ldsOff]);
  gld_lds16(gB + 32, &smem[12288 + 4096 + ldsOff]);
  __builtin_amdgcn_sched_barrier(0);
  asm volatile("s_waitcnt vmcnt(2)");
  bar();

  int s = 0;
  for (int kt = 0; kt < K; kt += 32) {
    if (kt + 64 < K) {
      const int ns = (s == 0) ? 2 : s - 1;  // (s+2)%3
      gld_lds16(gA + kt + 64, &smem[ns * 4096 + ldsOff]);
      gld_lds16(gB + kt + 64, &smem[12288 + ns * 4096 + ldsOff]);
    }
    const int sb = s * 4096;
    long af[4], bf[4];
    #pragma unroll
    for (int i = 0; i < 4; ++i) {
      af[i] = *(const long*)&smem[sb + aoff[i]];
      bf[i] = *(const long*)&smem[12288 + sb + boff[i]];
    }
    #pragma unroll
    for (int i = 0; i < 4; ++i)
      #pragma unroll
      for (int j = 0; j < 4; ++j)
        acc[i][j] = __builtin_amdgcn_mfma_f32_16x16x32_fp8_fp8(
            af[i], bf[j], acc[i][j], 0, 0, 0);
    if (kt + 32 < K) {
      __builtin_amdgcn_sched_barrier(0);
      if (kt + 64 < K) asm volatile("s_waitcnt vmcnt(2)");
      else             asm volatile("s_waitcnt vmcnt(0)");
      bar();
    }
    s = (s == 2) ? 0 : s + 1;
  }
  __syncthreads();  // all waves done reading stages before bounce overlay

  {  // EPI 6: PV
    const float* rsF = rsum + z * 4096;
    u16* outp = (u16*)outBv + z * ozs;
    u16* b16 = (u16*)smem;
    #pragma unroll
    for (int i = 0; i < 4; ++i) {
      int lm = wm * 64 + i * 16 + quad * 4;
      float rinv[4];
      #pragma unroll
      for (int r = 0; r < 4; ++r)
        rinv[r] = __builtin_amdgcn_rcpf(rsF[m0 + lm + r]);
      #pragma unroll
      for (int j = 0; j < 4; ++j) {
        int ln = wn * 64 + j * 16 + li;
        #pragma unroll
        for (int r = 0; r < 4; ++r)
          b16[(lm + r) * 136 + ln] = f2bf(acc[i][j][r] * rinv[r]);
      }
    }
    __syncthreads();
    int row = t >> 1, half = t & 1;
    const u16* src = &b16[row * 136 + half * 64];
    u16* dst = outp + (size_t)(m0 + row) * ldo + n0 + half * 64;
    #pragma unroll
    for (int cc = 0; cc < 8; ++cc)
      *(uint4*)(dst + cc * 8) = *(const uint4*)(src + cc * 8);
  }
}

// ------------- QK^T: pipelined 256x256-tile fp8 GEMM + exp + rowsum -------
// 8 waves (2x4), per-wave C = 128x64 (Mrep=8, Nrep=4), BK=64 as two BK=32
// panels. Triple-buffered LDS K-tiles (3 x 32KB), prefetch distance = 2
// tiles via global_load_lds, boundary wait = s_waitcnt vmcnt(4). 4 compute
// phases per K-tile (C-quadrants, 16 MFMA each).  Barrier/wait hygiene is
// m201-style: builtin s_barrier + clobber-free waitcnt asm + sched_barrier
// fences (a "memory" clobber forces vmcnt(0) before every barrier = full
// drain per phase, the round-1/3 stall).  Staging bank-swizzled (round-2
// scheme): chunk p = (2*row+half)^((row>>2)&7) via pre-swizzled global src.
__global__ __launch_bounds__(512, 2) void qk8p(
    const u8* __restrict__ A, const u8* __restrict__ B,
    float* __restrict__ rowsum, u8* __restrict__ outE) {
  // buffers: buf b at b*32768; within buf: A panels k16=0/1 at k*8192,
  // B at +16384 likewise. Epilogue bounce u8 [256][272] overlays smem.
  __shared__ __align__(16) u8 smem[98304];

  // XCD-contiguous work remap over the 1024-block grid (T1, bijective)
  int gblk = (blockIdx.z * 16 + blockIdx.y) * 16 + blockIdx.x;
  int work = (gblk & 7) * 128 + (gblk >> 3);
  int z  = work >> 8;
  int wr = work & 255;
  int by = wr >> 4, bx = wr & 15;
  const int m0 = by * 256, n0 = bx * 256;
  A += (size_t)z * 4096 * 1024;
  B += (size_t)z * 4096 * 1024;
  float* rsF = rowsum + (size_t)z * 4096;
  u8* outp = outE + (size_t)z * 4096 * 4096;

  const int t = threadIdx.x;
  const int lane = t & 63, w = t >> 6;
  const int wm = w >> 2, wn = w & 3;       // wave grid 2 (M) x 4 (N)
  const int quad = lane >> 4, li = lane & 15;

  // staging (pre-swizzled global source, linear LDS dest):
  // u = lane ^ ((lane>>3)&7); srow = u>>1 (0..31), shalf = u&1.
  const int us = lane ^ ((lane >> 3) & 7);
  const int srow = (us >> 1) & 31;
  const int shalf = us & 1;
  const u8* gA[2];
  const u8* gB[2];
  uint32_t lA[2], lB[2];
  #pragma unroll
  for (int g = 0; g < 2; ++g) {
    gA[g] = A + (size_t)(m0 + w * 32 + srow) * 1024 + g * 32 + shalf * 16;
    gB[g] = B + (size_t)(n0 + w * 32 + srow) * 1024 + g * 32 + shalf * 16;
    lA[g] = g * 8192 + w * 1024;
    lB[g] = 16384 + g * 8192 + w * 1024;
  }

  // frag read offsets (within a panel): region*1024 + p*16 + qlo,
  // p = (2*r5+h)^((r5>>2)&7), h = quad>>1, qlo = (quad&1)*8.
  const int h = quad >> 1, qlo = (quad & 1) * 8;
  int pa[4], pb[2];
  #pragma unroll
  for (int i = 0; i < 4; ++i) {
    int r5 = (i & 1) * 16 + li;
    int p = (2 * r5 + h) ^ ((r5 >> 2) & 7);
    pa[i] = (i >> 1) * 1024 + p * 16 + qlo;
  }
  #pragma unroll
  for (int j = 0; j < 2; ++j) {
    int r5 = j * 16 + li;
    int p = (2 * r5 + h) ^ ((r5 >> 2) & 7);
    pb[j] = p * 16 + qlo;
  }
  const uint32_t aB0 = (uint32_t)wm * 4096;          // + ihalf*2048 + pa[i]
  const uint32_t bB0 = 16384 + (uint32_t)wn * 2048;  // + jhalf*1024 + pb[j]

  f32x4 zero = {0.f, 0.f, 0.f, 0.f};
  f32x4 acc[8][4];
  #pragma unroll
  for (int i = 0; i < 8; ++i)
    #pragma unroll
    for (int j = 0; j < 4; ++j) acc[i][j] = zero;

  // prologue: stage tiles 0 and 1 (issue order fixed: A0,B0,A1,B1 per tile)
  #pragma unroll
  for (int tt = 0; tt < 2; ++tt) {
    gld_lds16(gA[0] + tt * 64, &smem[tt * 32768 + lA[0]]);
    gld_lds16(gB[0] + tt * 64, &smem[tt * 32768 + lB[0]]);
    gld_lds16(gA[1] + tt * 64, &smem[tt * 32768 + lA[1]]);
    gld_lds16(gB[1] + tt * 64, &smem[tt * 32768 + lB[1]]);
  }
  __builtin_amdgcn_sched_barrier(0);
  asm volatile("s_waitcnt vmcnt(4)");  // tile0 landed
  bar();

  uint32_t bo = 0, bp = 65536;
  #pragma unroll 1
  for (int tt = 0; tt < 8; ++tt) {
    const bool pf = tt < 6;            // prefetch tile tt+2 exists
    const int kp = tt * 64 + 128;      // its K offset
    long a[8], b0[4], b1[4];

    // ---- phase 0: read A-half0 + B-half0, prefetch A panel0 ----
    #pragma unroll
    for (int i = 0; i < 4; ++i)
      #pragma unroll
      for (int k = 0; k < 2; ++k)
        a[i * 2 + k] = *(const long*)&smem[bo + k * 8192 + aB0 + pa[i]];
    #pragma unroll
    for (int j = 0; j < 2; ++j)
      #pragma unroll
      for (int k = 0; k < 2; ++k)
        b0[j * 2 + k] = *(const long*)&smem[bo + k * 8192 + bB0 + pb[j]];
    if (pf) gld_lds16(gA[0] + kp, &smem[bp + lA[0]]);
    bar();
    asm volatile("s_waitcnt lgkmcnt(0)");
    __builtin_amdgcn_sched_barrier(0);
    __builtin_amdgcn_s_setprio(1);
    #pragma unroll
    for (int i = 0; i < 4; ++i)
      #pragma unroll
      for (int j = 0; j < 2; ++j) {
        acc[i][j] = __builtin_amdgcn_mfma_f32_16x16x32_fp8_fp8(
            a[i * 2 + 0], b0[j * 2 + 0], acc[i][j], 0, 0, 0);
        acc[i][j] = __builtin_amdgcn_mfma_f32_16x16x32_fp8_fp8(
            a[i * 2 + 1], b0[j * 2 + 1], acc[i][j], 0, 0, 0);
      }
    __builtin_amdgcn_s_setprio(0);
    bar();

    // ---- phase 1: read B-half1, prefetch B panel0 ----
    #pragma unroll
    for (int j = 0; j < 2; ++j)
      #pragma unroll
      for (int k = 0; k < 2; ++k)
        b1[j * 2 + k] =
            *(const long*)&smem[bo + k * 8192 + bB0 + 1024 + pb[j]];
    if (pf) gld_lds16(gB[0] + kp, &smem[bp + lB[0]]);
    bar();
    asm volatile("s_waitcnt lgkmcnt(0)");
    __builtin_amdgcn_sched_barrier(0);
    __builtin_amdgcn_s_setprio(1);
    #pragma unroll
    for (int i = 0; i < 4; ++i)
      #pragma unroll
      for (int j = 0; j < 2; ++j) {
        acc[i][2 + j] = __builtin_amdgcn_mfma_f32_16x16x32_fp8_fp8(
            a[i * 2 + 0], b1[j * 2 + 0], acc[i][2 + j], 0, 0, 0);
        acc[i][2 + j] = __builtin_amdgcn_mfma_f32_16x16x32_fp8_fp8(
            a[i * 2 + 1], b1[j * 2 + 1], acc[i][2 + j], 0, 0, 0);
      }
    __builtin_amdgcn_s_setprio(0);
    bar();

    // ---- phase 2: read A-half1 (reuse a[]), prefetch A panel1 ----
    #pragma unroll
    for (int i = 0; i < 4; ++i)
      #pragma unroll
      for (int k = 0; k < 2; ++k)
        a[i * 2 + k] =
            *(const long*)&smem[bo + k * 8192 + aB0 + 2048 + pa[i]];
    if (pf) gld_lds16(gA[1] + kp, &smem[bp + lA[1]]);
    bar();
    asm volatile("s_waitcnt lgkmcnt(0)");
    __builtin_amdgcn_sched_barrier(0);
    __builtin_amdgcn_s_setprio(1);
    #pragma unroll
    for (int i = 0; i < 4; ++i)
      #pragma unroll
      for (int j = 0; j < 2; ++j) {
        acc[4 + i][2 + j] = __builtin_amdgcn_mfma_f32_16x16x32_fp8_fp8(
            a[i * 2 + 0], b1[j * 2 + 0], acc[4 + i][2 + j], 0, 0, 0);
        acc[4 + i][2 + j] = __builtin_amdgcn_mfma_f32_16x16x32_fp8_fp8(
            a[i * 2 + 1], b1[j * 2 + 1], acc[4 + i][2 + j], 0, 0, 0);
      }
    __builtin_amdgcn_s_setprio(0);
    bar();

    // ---- phase 3: no reads (A1,B0 live), prefetch B panel1, boundary ----
    if (pf) {
      gld_lds16(gB[1] + kp, &smem[bp + lB[1]]);
      __builtin_amdgcn_sched_barrier(0);
      asm volatile("s_waitcnt vmcnt(4)");  // tile tt+1 landed
    } else {
      __builtin_amdgcn_sched_barrier(0);
      asm volatile("s_waitcnt vmcnt(0)");
    }
    bar();
    __builtin_amdgcn_s_setprio(1);
    #pragma unroll
    for (int i = 0; i < 4; ++i)
      #pragma unroll
      for (int j = 0; j < 2; ++j) {
        acc[4 + i][j] = __builtin_amdgcn_mfma_f32_16x16x32_fp8_fp8(
            a[i * 2 + 0], b0[j * 2 + 0], acc[4 + i][j], 0, 0, 0);
        acc[4 + i][j] = __builtin_amdgcn_mfma_f32_16x16x32_fp8_fp8(
            a[i * 2 + 1], b0[j * 2 + 1], acc[4 + i][j], 0, 0, 0);
      }
    __builtin_amdgcn_s_setprio(0);
    bar();

    bo += 32768; if (bo == 98304) bo = 0;
    bp += 32768; if (bp == 98304) bp = 0;
  }

  // ---- epilogue: exp + clamp, rowsum atomics, fp8 bounce + coalesced out --
  u8* bnc = smem;
  #pragma unroll
  for (int I = 0; I < 8; ++I) {
    int lm = wm * 128 + I * 16 + quad * 4;
    float rs[4] = {0.f, 0.f, 0.f, 0.f};
    #pragma unroll
    for (int j = 0; j < 4; ++j) {
      int ln = wn * 64 + j * 16 + li;
      #pragma unroll
      for (int r = 0; r < 4; ++r) {
        float e = fminf(__expf(acc[I][j][r]), 448.f);
        bnc[(lm + r) * 272 + ln] = f2f8(e);
        rs[r] += e;
      }
    }
    #pragma unroll
    for (int r = 0; r < 4; ++r) {
      rs[r] += __shfl_xor(rs[r], 1);
      rs[r] += __shfl_xor(rs[r], 2);
      rs[r] += __shfl_xor(rs[r], 4);
      rs[r] += __shfl_xor(rs[r], 8);
    }
    if (li == 0) {
      #pragma unroll
      for (int r = 0; r < 4; ++r) atomicAdd(&rsF[m0 + lm + r], rs[r]);
    }
  }
  __syncthreads();
  {
    int row = t >> 1, half = t & 1;
    const u8* src = &bnc[row * 272 + half * 128];
    u8* dst = outp + (size_t)(m0 + row) * 4096 + n0 + half * 128;
    #pragma unroll
    for (int cc = 0; cc < 8; ++cc)
      *(uint4*)(dst + cc * 16) = *(const uint4*)(src + cc * 16);
  }
}

extern "C" void kernel_launch(void* const* d_in, const int* in_sizes, int n_in,
                              void* d_out, int out_size, void* d_ws, size_t ws_size,
                              hipStream_t stream) {
  (void)in_sizes; (void)n_in; (void)out_size; (void)ws_size;
  const float* x      = (const float*)d_in[0];
  const float* gamma  = (const float*)d_in[1];
  const float* beta   = (const float*)d_in[2];
  const float* w_qkv  = (const float*)d_in[3];
  const float* b_qkv  = (const float*)d_in[4];
  const float* w_proj = (const float*)d_in[5];
  const float* b_proj = (const float*)d_in[6];
  float* out = (float*)d_out;

  const int C = 512, N = 4096;
  const size_t NC = (size_t)N * C;
  const float scale = 0.21022410381342863f;  // 512^-0.25

  char* ws = (char*)d_ws;
  size_t off = 0;
  auto alloc = [&](size_t bytes) -> char* {
    char* p = ws + off; off += (bytes + 255) & ~(size_t)255; return p;
  };
  u16*   wq_bf  = (u16*)alloc((size_t)1536 * 512 * 2);
  u16*   wp_bf  = (u16*)alloc((size_t)512 * 512 * 2);
  float* stats  = (float*)alloc(128 * 2 * 4);
  float* rowsum = (float*)alloc((size_t)4 * N * 4);
  u16*   xnT    = (u16*)alloc((size_t)4 * NC * 2);      // [b][n][c] bf16
  u8*    qkT    = (u8*)alloc((size_t)4 * N * 1024);     // [b][i][o] fp8, o<1024
  u8*    vbf    = (u8*)alloc((size_t)4 * 512 * 4096);   // [b][c][j] fp8
  u16*   ao     = (u16*)alloc((size_t)4 * NC * 2);      // [b][i][c] bf16
  u8*    E      = (u8*)alloc((size_t)4 * N * N);        // [b][i][j] fp8

  cvt_weights<<<3072, 256, 0, stream>>>(w_qkv, w_proj, wq_bf, wp_bf);
  gn_stats<<<128, 256, 0, stream>>>(x, stats);
  gn_norm_t<<<dim3(64, 8, 4), 256, 0, stream>>>(x, stats, gamma, beta, xnT);
  hipMemsetAsync(rowsum, 0, (size_t)4 * N * 4, stream);

  // qkT[b][i][o] = fp8((sum_c xnT[b][i][c]*wq[o][c] + b_qkv[o]) * scale)
  gemm_nt<4><<<dim3(8, 32, 4), 256, 0, stream>>>(
      xnT, wq_bf, 512, 512, 512, b_qkv, nullptr, scale,
      nullptr, qkT, 1024, NC, 0, (size_t)N * 1024);
  // vbf[b][c][j] = fp8(sum_k wq[1024+c][k]*xnT[b][j][k] + b_qkv[1024+c])
  gemm_nt<5><<<dim3(32, 4, 4), 256, 0, stream>>>(
      wq_bf + (size_t)1024 * 512, xnT, 512, 512, 512, b_qkv + 1024, nullptr,
      0.f, nullptr, vbf, 4096, 0, NC, (size_t)512 * 4096);
  // E[b][i][j] = fp8(exp(S)), rowsum[b][i] += partials (pipelined 256^2,
  // clean barriers + counted vmcnt)
  qk8p<<<dim3(16, 16, 4), 512, 0, stream>>>(qkT, qkT + 512, rowsum, E);
  // ao[b][i][c] = bf16((sum_j E*v) * rcp(rowsum[b][i]))  (K=4096, fp8 MFMA)
  gemm_nt8<6, 0><<<dim3(4, 32, 4), 256, 0, stream>>>(
      E, vbf, 4096, 4096, 4096, rowsum, nullptr,
      ao, 512, (size_t)N * N, (size_t)512 * 4096, NC);
  // out[b][o][n] = sum_c wp[o][c]*ao[b][n][c] + b_proj[o] + x[b][o][n]
  gemm_nt<3><<<dim3(32, 4, 4), 256, 0, stream>>>(
      wp_bf, ao, 512, 512, 512, b_proj, x, 0.f,
      out, nullptr, 4096, 0, NC, NC);
}

// Round 5
// 417.641 us; speedup vs baseline: 1.0254x; 1.0079x over previous
//
#include <hip/hip_runtime.h>
#include <hip/hip_fp8.h>
#include <stdint.h>

typedef unsigned short u16;
typedef unsigned char u8;
typedef __bf16 bf16x8 __attribute__((ext_vector_type(8)));
typedef float f32x4 __attribute__((ext_vector_type(4)));

__device__ __forceinline__ u16 f2bf(float f) {
  union { float f; unsigned u; } v; v.f = f;
  return (u16)((v.u + 0x7FFFu + ((v.u >> 16) & 1u)) >> 16);
}
__device__ __forceinline__ u8 f2f8(float f) {
  __hip_fp8_e4m3 h(f);
  return (u8)h.__x;
}

// async 16B global -> LDS (wave-uniform LDS base; HW writes base + lane*16)
__device__ __forceinline__ void gld_lds16(const void* g, void* l) {
  uint32_t lo = (uint32_t)(uintptr_t)l;
  lo = __builtin_amdgcn_readfirstlane(lo);
  auto* lp = (__attribute__((address_space(3))) uint32_t*)(uintptr_t)lo;
  auto* gp = (const __attribute__((address_space(1))) uint32_t*)(uintptr_t)g;
  __builtin_amdgcn_global_load_lds(gp, lp, 16, 0, 0);
}

// clobber-free barrier, fenced so no memory op crosses at schedule time.
__device__ __forceinline__ void bar() {
  __builtin_amdgcn_sched_barrier(0);
  __builtin_amdgcn_s_barrier();
  __builtin_amdgcn_sched_barrier(0);
}

// ---------------- weight fp32 -> bf16 ----------------
__global__ __launch_bounds__(256) void cvt_weights(
    const float* __restrict__ wq, const float* __restrict__ wp,
    u16* __restrict__ oq, u16* __restrict__ op) {
  int i = blockIdx.x * 256 + threadIdx.x;
  if (i < 1536 * 512) oq[i] = f2bf(wq[i]);
  if (i < 512 * 512)  op[i] = f2bf(wp[i]);
}

// ---------------- group norm stats ----------------
__global__ __launch_bounds__(256) void gn_stats(const float* __restrict__ x,
                                                float* __restrict__ stats) {
  int bg = blockIdx.x;  // 0..127
  const float* p = x + (size_t)bg * 65536;
  float s = 0.f, sq = 0.f;
  for (int i = threadIdx.x * 4; i < 65536; i += 1024) {
    float4 v = *(const float4*)(p + i);
    s += v.x + v.y + v.z + v.w;
    sq += v.x * v.x + v.y * v.y + v.z * v.z + v.w * v.w;
  }
  int lane = threadIdx.x & 63, w = threadIdx.x >> 6;
  for (int off = 32; off; off >>= 1) {
    s += __shfl_down(s, off);
    sq += __shfl_down(sq, off);
  }
  __shared__ float ls[4], lq[4];
  if (lane == 0) { ls[w] = s; lq[w] = sq; }
  __syncthreads();
  if (threadIdx.x == 0) {
    float S = ls[0] + ls[1] + ls[2] + ls[3];
    float Q = lq[0] + lq[1] + lq[2] + lq[3];
    float mean = S * (1.f / 65536.f);
    float var = Q * (1.f / 65536.f) - mean * mean;
    stats[bg * 2] = mean;
    stats[bg * 2 + 1] = rsqrtf(var + 1e-6f);
  }
}

// ---------------- group norm + transpose: x[b][c][n] -> xnT[b][n][c] bf16 ----
__global__ __launch_bounds__(256) void gn_norm_t(const float* __restrict__ x,
    const float* __restrict__ stats, const float* __restrict__ gamma,
    const float* __restrict__ beta, u16* __restrict__ xnT) {
  __shared__ u16 tile[64][72];
  int b = blockIdx.z;
  int c0 = blockIdx.y * 64, n0 = blockIdx.x * 64;
  int t = threadIdx.x;
  int cl = t >> 2, ng = (t & 3) * 16;
  int c = c0 + cl;
  float mean = stats[(b * 32 + (c >> 4)) * 2];
  float rstd = stats[(b * 32 + (c >> 4)) * 2 + 1];
  float a = gamma[c] * rstd;
  float b2 = beta[c] - mean * a;
  const float* src = x + ((size_t)b * 512 + c) * 4096 + n0 + ng;
  u16 e[16];
  #pragma unroll
  for (int q = 0; q < 4; ++q) {
    float4 v = *(const float4*)(src + q * 4);
    e[q * 4 + 0] = f2bf(v.x * a + b2);
    e[q * 4 + 1] = f2bf(v.y * a + b2);
    e[q * 4 + 2] = f2bf(v.z * a + b2);
    e[q * 4 + 3] = f2bf(v.w * a + b2);
  }
  #pragma unroll
  for (int j = 0; j < 16; ++j) tile[ng + j][cl] = e[j];
  __syncthreads();
  int nl = t >> 2, cg = (t & 3) * 16;
  uint4 w0 = *(const uint4*)&tile[nl][cg];
  uint4 w1 = *(const uint4*)&tile[nl][cg + 8];
  u16* dst = xnT + ((size_t)b * 4096 + n0 + nl) * 512 + c0 + cg;
  *(uint4*)dst = w0;
  *(uint4*)(dst + 8) = w1;
}

// ------------- bf16 NT GEMM: C[m][n] = sum_k A[m*lda+k]*B[n*ldb+k] --------
// 128x128 tile, BK=32, dbuf LDS + global_load_lds.
// EPI: 3 = fp32 out + bias[m] + resid (proj)
//      4 = fp8 out, (acc+bias[n])*scale  (qk: m=spatial, n=channel)
//      5 = fp8 out, acc+bias[m]          (v:  m=channel, n=spatial)
template<int EPI>
__global__ __launch_bounds__(256) void gemm_nt(
    const u16* __restrict__ A, const u16* __restrict__ B,
    int lda, int ldb, int K,
    const float* __restrict__ bias, const float* __restrict__ resid,
    float scale, float* __restrict__ outF, void* __restrict__ outBv, int ldo,
    size_t azs, size_t bzs, size_t ozs) {
  __shared__ __align__(16) u16 smem[16384];
  const size_t z = blockIdx.z;
  A += z * azs; B += z * bzs;
  const int t = threadIdx.x;
  const int wave = t >> 6, lane = t & 63;
  const int wm = wave >> 1, wn = wave & 1;
  const int quad = lane >> 4, li = lane & 15;
  const int m0 = blockIdx.y * 128, n0 = blockIdx.x * 128;

  const int srow = lane >> 2;
  const int scol = (lane & 3) * 8;
  const u16* gA[2];
  const u16* gB[2];
  int ldsOff[2];
  #pragma unroll
  for (int r = 0; r < 2; ++r) {
    int rb = wave + 4 * r;
    gA[r] = A + (size_t)(m0 + rb * 16 + srow) * lda + scol;
    gB[r] = B + (size_t)(n0 + rb * 16 + srow) * ldb + scol;
    ldsOff[r] = rb * 512;
  }

  f32x4 zero = {0.f, 0.f, 0.f, 0.f};
  f32x4 acc[4][4];
  #pragma unroll
  for (int i = 0; i < 4; ++i)
    #pragma unroll
    for (int j = 0; j < 4; ++j) acc[i][j] = zero;

  #pragma unroll
  for (int r = 0; r < 2; ++r) {
    gld_lds16(gA[r], &smem[ldsOff[r]]);
    gld_lds16(gB[r], &smem[8192 + ldsOff[r]]);
  }
  __syncthreads();

  for (int kt = 0; kt < K; kt += 32) {
    const int s = (kt >> 5) & 1;
    if (kt + 32 < K) {
      const int ns = s ^ 1;
      #pragma unroll
      for (int r = 0; r < 2; ++r) {
        gld_lds16(gA[r] + kt + 32, &smem[ns * 4096 + ldsOff[r]]);
        gld_lds16(gB[r] + kt + 32, &smem[8192 + ns * 4096 + ldsOff[r]]);
      }
    }
    bf16x8 af[4], bf[4];
    #pragma unroll
    for (int i = 0; i < 4; ++i) {
      af[i] = *(const bf16x8*)&smem[s * 4096 +
               (wm * 64 + i * 16 + li) * 32 + quad * 8];
      bf[i] = *(const bf16x8*)&smem[8192 + s * 4096 +
               (wn * 64 + i * 16 + li) * 32 + quad * 8];
    }
    #pragma unroll
    for (int i = 0; i < 4; ++i)
      #pragma unroll
      for (int j = 0; j < 4; ++j)
        acc[i][j] = __builtin_amdgcn_mfma_f32_16x16x32_bf16(
            af[i], bf[j], acc[i][j], 0, 0, 0);
    __syncthreads();
  }

  if (EPI == 3) {
    outF += z * ozs; resid += z * ozs;
    #pragma unroll
    for (int i = 0; i < 4; ++i)
      #pragma unroll
      for (int j = 0; j < 4; ++j) {
        int mB = m0 + wm * 64 + i * 16 + quad * 4;
        int n = n0 + wn * 64 + j * 16 + li;
        #pragma unroll
        for (int r = 0; r < 4; ++r) {
          int m = mB + r;
          float v = acc[i][j][r] + bias[m] + resid[(size_t)m * ldo + n];
          outF[(size_t)m * ldo + n] = v;
        }
      }
    return;
  }

  // fp8 outputs (EPI 4/5): bounce through LDS, coalesced stores
  u8* out8 = (u8*)outBv + z * ozs;
  u8* bnc = (u8*)smem;
  #pragma unroll
  for (int i = 0; i < 4; ++i) {
    int lm = wm * 64 + i * 16 + quad * 4;
    #pragma unroll
    for (int j = 0; j < 4; ++j) {
      int ln = wn * 64 + j * 16 + li;
      #pragma unroll
      for (int r = 0; r < 4; ++r) {
        float v = acc[i][j][r];
        u8 o;
        if (EPI == 4) o = f2f8((v + bias[n0 + ln]) * scale);
        else          o = f2f8(v + bias[m0 + lm + r]);
        bnc[(lm + r) * 144 + ln] = o;
      }
    }
  }
  __syncthreads();
  {
    int row = t >> 1, half = t & 1;
    const u8* src = &bnc[row * 144 + half * 64];
    u8* dst = out8 + (size_t)(m0 + row) * ldo + n0 + half * 64;
    #pragma unroll
    for (int cc = 0; cc < 4; ++cc)
      *(uint4*)(dst + cc * 16) = *(const uint4*)(src + cc * 16);
  }
}

// ------------- fp8 NT GEMM (QK): C[m][n] = sum_k A[m*lda+k]*B[n*ldb+k] ----
// 128x128 tile, BK=32/stage, 3-stage LDS pipeline (prefetch distance 2) with
// counted clobber-free s_waitcnt vmcnt(2) + builtin s_barrier.  Frag reads
// swizzle-mapped (2-way max conflict) via pre-swizzled GLOBAL source.
// EPI: 7 = fp8 out exp(acc) (clamped 448), atomicAdd row-sums into outF
template<int EPI, int SWZ>
__global__ __launch_bounds__(256) void gemm_nt8(
    const u8* __restrict__ A, const u8* __restrict__ B,
    int lda, int ldb, int K,
    const float* __restrict__ rsum, float* __restrict__ outF,
    void* __restrict__ outBv, int ldo,
    size_t azs, size_t bzs, size_t ozs) {
  // stages (bytes): A s*4096 in [0,12288), B 12288+s*4096 in [12288,24576)
  // bounce overlay: EPI7 u8 128x144 = 18432
  __shared__ __align__(16) u8 smem[24576];
  const size_t z = blockIdx.z;
  A += z * azs; B += z * bzs;
  int bx = blockIdx.x, by = blockIdx.y;
  if (SWZ) {  // 16x16 super-tiles over a 32x32 grid
    int lin = by * 32 + bx;
    int tt = lin >> 8, w = lin & 255;
    by = (tt >> 1) * 16 + (w >> 4);
    bx = (tt & 1) * 16 + (w & 15);
  }
  const int t = threadIdx.x;
  const int wave = t >> 6, lane = t & 63;
  const int wm = wave >> 1, wn = wave & 1;
  const int quad = lane >> 4, li = lane & 15;
  const int m0 = by * 128, n0 = bx * 128;

  // staging: pre-swizzled source.  u = l ^ ((l>>3)&7); row = u>>1, half = u&1.
  const int us = lane ^ ((lane >> 3) & 7);
  const int srow = (us >> 1) & 31;
  const int shalf = us & 1;
  const u8* gA = A + (size_t)(m0 + wave * 32 + srow) * lda + shalf * 16;
  const u8* gB = B + (size_t)(n0 + wave * 32 + srow) * ldb + shalf * 16;
  const int ldsOff = wave * 1024;

  // frag read offsets: p = (2*r5+h) ^ ((r5>>2)&7)
  const int h = quad >> 1, qlo = (quad & 1) * 8;
  int aoff[4], boff[4];
  #pragma unroll
  for (int i = 0; i < 4; ++i) {
    int r5 = (i & 1) * 16 + li;
    int p = (2 * r5 + h) ^ ((r5 >> 2) & 7);
    aoff[i] = (wm * 2 + (i >> 1)) * 1024 + p * 16 + qlo;
    boff[i] = (wn * 2 + (i >> 1)) * 1024 + p * 16 + qlo;
  }

  f32x4 zero = {0.f, 0.f, 0.f, 0.f};
  f32x4 acc[4][4];
  #pragma unroll
  for (int i = 0; i < 4; ++i)
    #pragma unroll
    for (int j = 0; j < 4; ++j) acc[i][j] = zero;

  // prologue: stage kt=0 and kt=32, wait only for kt=0 (vmcnt(2))
  gld_lds16(gA, &smem[ldsOff]);
  gld_lds16(gB, &smem[12288 + ldsOff]);
  gld_lds16(gA + 32, &smem[4096 + ldsOff]);
  gld_lds16(gB + 32, &smem[12288 + 4096 + ldsOff]);
  __builtin_amdgcn_sched_barrier(0);
  asm volatile("s_waitcnt vmcnt(2)");
  bar();

  int s = 0;
  for (int kt = 0; kt < K; kt += 32) {
    if (kt + 64 < K) {
      const int ns = (s == 0) ? 2 : s - 1;  // (s+2)%3
      gld_lds16(gA + kt + 64, &smem[ns * 4096 + ldsOff]);
      gld_lds16(gB + kt + 64, &smem[12288 + ns * 4096 + ldsOff]);
    }
    const int sb = s * 4096;
    long af[4], bf[4];
    #pragma unroll
    for (int i = 0; i < 4; ++i) {
      af[i] = *(const long*)&smem[sb + aoff[i]];
      bf[i] = *(const long*)&smem[12288 + sb + boff[i]];
    }
    #pragma unroll
    for (int i = 0; i < 4; ++i)
      #pragma unroll
      for (int j = 0; j < 4; ++j)
        acc[i][j] = __builtin_amdgcn_mfma_f32_16x16x32_fp8_fp8(
            af[i], bf[j], acc[i][j], 0, 0, 0);
    if (kt + 32 < K) {
      __builtin_amdgcn_sched_barrier(0);
      if (kt + 64 < K) asm volatile("s_waitcnt vmcnt(2)");
      else             asm volatile("s_waitcnt vmcnt(0)");
      bar();
    }
    s = (s == 2) ? 0 : s + 1;
  }
  __syncthreads();  // all waves done reading stages before bounce overlay

  {  // EPI 7: exp + clamp, rowsum atomics, fp8 bounce + coalesced out
    float* rsF = outF + z * 4096;
    u8* outE = (u8*)outBv + z * ozs;
    #pragma unroll
    for (int i = 0; i < 4; ++i) {
      int lm = wm * 64 + i * 16 + quad * 4;
      float rs[4] = {0.f, 0.f, 0.f, 0.f};
      #pragma unroll
      for (int j = 0; j < 4; ++j) {
        int ln = wn * 64 + j * 16 + li;
        #pragma unroll
        for (int r = 0; r < 4; ++r) {
          float e = fminf(__expf(acc[i][j][r]), 448.f);
          smem[(lm + r) * 144 + ln] = f2f8(e);
          rs[r] += e;
        }
      }
      #pragma unroll
      for (int r = 0; r < 4; ++r) {
        rs[r] += __shfl_xor(rs[r], 1);
        rs[r] += __shfl_xor(rs[r], 2);
        rs[r] += __shfl_xor(rs[r], 4);
        rs[r] += __shfl_xor(rs[r], 8);
      }
      if (li == 0) {
        #pragma unroll
        for (int r = 0; r < 4; ++r) atomicAdd(&rsF[m0 + lm + r], rs[r]);
      }
    }
    __syncthreads();
    int row = t >> 1, half = t & 1;
    const u8* src = &smem[row * 144 + half * 64];
    u8* dst = outE + (size_t)(m0 + row) * ldo + n0 + half * 64;
    #pragma unroll
    for (int cc = 0; cc < 4; ++cc)
      *(uint4*)(dst + cc * 16) = *(const uint4*)(src + cc * 16);
  }
}

// ------------- PV fp8 GEMM: ao[i][c] = (sum_j E[i][j]*v[c][j]) / rowsum[i] -
// 128x64 tile (M=i rows of E, N=c cols) -> grid (32,8,4) = 1024 blocks =
// 4 blocks/CU (vs 2 at 128x128): doubles resident blocks so the 2-phase
// vmcnt drain of one block hides under another block's MFMA (TLP, the m97
// mechanism).  Grid is (m-tiles, c-tiles): the 8 c-siblings sharing an
// E-strip sit at stride-32 block ids -> same XCD -> strip read once per L2.
// 3-stage pipeline, counted vmcnt, swizzled staging/frag reads as gemm_nt8.
// LDS: A stages s*4096 [0,12288); B stages 12288+s*2048 [12288,18432);
// bounce u16[128][72] overlays [0,18432).
__global__ __launch_bounds__(256) void gemm_pv(
    const u8* __restrict__ A, const u8* __restrict__ B,
    const float* __restrict__ rsum, u16* __restrict__ outp_,
    size_t azs, size_t bzs, size_t ozs) {
  __shared__ __align__(16) u8 smem[18432];
  const int lda = 4096, ldb = 4096, K = 4096, ldo = 512;
  const size_t z = blockIdx.z;
  A += z * azs; B += z * bzs;
  const int t = threadIdx.x;
  const int wave = t >> 6, lane = t & 63;
  const int wm = wave >> 1, wn = wave & 1;
  const int quad = lane >> 4, li = lane & 15;
  const int m0 = blockIdx.x * 128, n0 = blockIdx.y * 64;

  const int us = lane ^ ((lane >> 3) & 7);
  const int srow = (us >> 1) & 31;
  const int shalf = us & 1;
  // A staged by all 4 waves (rows wave*32..+32); B by waves 0,1 only.
  const bool doB = wave < 2;
  const u8* gA = A + (size_t)(m0 + wave * 32 + srow) * lda + shalf * 16;
  const u8* gB = B + (size_t)(n0 + (wave & 1) * 32 + srow) * ldb + shalf * 16;
  const int ldsA = wave * 1024;
  const int ldsB = (wave & 1) * 1024;  // within B stage

  const int h = quad >> 1, qlo = (quad & 1) * 8;
  int aoff[4], boff[2];
  #pragma unroll
  for (int i = 0; i < 4; ++i) {
    int r5 = (i & 1) * 16 + li;
    int p = (2 * r5 + h) ^ ((r5 >> 2) & 7);
    aoff[i] = (wm * 2 + (i >> 1)) * 1024 + p * 16 + qlo;
  }
  #pragma unroll
  for (int j = 0; j < 2; ++j) {
    int r5 = j * 16 + li;
    int p = (2 * r5 + h) ^ ((r5 >> 2) & 7);
    boff[j] = wn * 1024 + p * 16 + qlo;
  }

  f32x4 zero = {0.f, 0.f, 0.f, 0.f};
  f32x4 acc[4][2];
  #pragma unroll
  for (int i = 0; i < 4; ++i)
    #pragma unroll
    for (int j = 0; j < 2; ++j) acc[i][j] = zero;

  // prologue: stage kt=0 and kt=32 (per-wave order: A0[,B0],A1[,B1])
  gld_lds16(gA, &smem[ldsA]);
  if (doB) gld_lds16(gB, &smem[12288 + ldsB]);
  gld_lds16(gA + 32, &smem[4096 + ldsA]);
  if (doB) gld_lds16(gB + 32, &smem[12288 + 2048 + ldsB]);
  __builtin_amdgcn_sched_barrier(0);
  if (doB) asm volatile("s_waitcnt vmcnt(2)");
  else     asm volatile("s_waitcnt vmcnt(1)");
  bar();

  int s = 0;
  for (int kt = 0; kt < K; kt += 32) {
    if (kt + 64 < K) {
      const int ns = (s == 0) ? 2 : s - 1;  // (s+2)%3
      gld_lds16(gA + kt + 64, &smem[ns * 4096 + ldsA]);
      if (doB) gld_lds16(gB + kt + 64, &smem[12288 + ns * 2048 + ldsB]);
    }
    const int sbA = s * 4096, sbB = 12288 + s * 2048;
    long af[4], bf[2];
    #pragma unroll
    for (int i = 0; i < 4; ++i) af[i] = *(const long*)&smem[sbA + aoff[i]];
    #pragma unroll
    for (int j = 0; j < 2; ++j) bf[j] = *(const long*)&smem[sbB + boff[j]];
    #pragma unroll
    for (int i = 0; i < 4; ++i)
      #pragma unroll
      for (int j = 0; j < 2; ++j)
        acc[i][j] = __builtin_amdgcn_mfma_f32_16x16x32_fp8_fp8(
            af[i], bf[j], acc[i][j], 0, 0, 0);
    if (kt + 32 < K) {
      __builtin_amdgcn_sched_barrier(0);
      if (kt + 64 < K) {
        if (doB) asm volatile("s_waitcnt vmcnt(2)");
        else     asm volatile("s_waitcnt vmcnt(1)");
      } else {
        asm volatile("s_waitcnt vmcnt(0)");
      }
      bar();
    }
    s = (s == 2) ? 0 : s + 1;
  }
  __syncthreads();  // done reading stages before bounce overlay

  {  // epilogue: scale by rcp(rowsum), bf16 bounce + coalesced stores
    const float* rsF = rsum + z * 4096;
    u16* outp = outp_ + z * ozs;
    u16* b16 = (u16*)smem;
    #pragma unroll
    for (int i = 0; i < 4; ++i) {
      int lm = wm * 64 + i * 16 + quad * 4;
      float rinv[4];
      #pragma unroll
      for (int r = 0; r < 4; ++r)
        rinv[r] = __builtin_amdgcn_rcpf(rsF[m0 + lm + r]);
      #pragma unroll
      for (int j = 0; j < 2; ++j) {
        int ln = wn * 32 + j * 16 + li;
        #pragma unroll
        for (int r = 0; r < 4; ++r)
          b16[(lm + r) * 72 + ln] = f2bf(acc[i][j][r] * rinv[r]);
      }
    }
    __syncthreads();
    int row = t >> 1, half = t & 1;
    const u16* src = &b16[row * 72 + half * 32];
    u16* dst = outp + (size_t)(m0 + row) * ldo + n0 + half * 32;
    #pragma unroll
    for (int cc = 0; cc < 4; ++cc)
      *(uint4*)(dst + cc * 8) = *(const uint4*)(src + cc * 8);
  }
}

extern "C" void kernel_launch(void* const* d_in, const int* in_sizes, int n_in,
                              void* d_out, int out_size, void* d_ws, size_t ws_size,
                              hipStream_t stream) {
  (void)in_sizes; (void)n_in; (void)out_size; (void)ws_size;
  const float* x      = (const float*)d_in[0];
  const float* gamma  = (const float*)d_in[1];
  const float* beta   = (const float*)d_in[2];
  const float* w_qkv  = (const float*)d_in[3];
  const float* b_qkv  = (const float*)d_in[4];
  const float* w_proj = (const float*)d_in[5];
  const float* b_proj = (const float*)d_in[6];
  float* out = (float*)d_out;

  const int C = 512, N = 4096;
  const size_t NC = (size_t)N * C;
  const float scale = 0.21022410381342863f;  // 512^-0.25

  char* ws = (char*)d_ws;
  size_t off = 0;
  auto alloc = [&](size_t bytes) -> char* {
    char* p = ws + off; off += (bytes + 255) & ~(size_t)255; return p;
  };
  u16*   wq_bf  = (u16*)alloc((size_t)1536 * 512 * 2);
  u16*   wp_bf  = (u16*)alloc((size_t)512 * 512 * 2);
  float* stats  = (float*)alloc(128 * 2 * 4);
  float* rowsum = (float*)alloc((size_t)4 * N * 4);
  u16*   xnT    = (u16*)alloc((size_t)4 * NC * 2);      // [b][n][c] bf16
  u8*    qkT    = (u8*)alloc((size_t)4 * N * 1024);     // [b][i][o] fp8, o<1024
  u8*    vbf    = (u8*)alloc((size_t)4 * 512 * 4096);   // [b][c][j] fp8
  u16*   ao     = (u16*)alloc((size_t)4 * NC * 2);      // [b][i][c] bf16
  u8*    E      = (u8*)alloc((size_t)4 * N * N);        // [b][i][j] fp8

  cvt_weights<<<3072, 256, 0, stream>>>(w_qkv, w_proj, wq_bf, wp_bf);
  gn_stats<<<128, 256, 0, stream>>>(x, stats);
  gn_norm_t<<<dim3(64, 8, 4), 256, 0, stream>>>(x, stats, gamma, beta, xnT);
  hipMemsetAsync(rowsum, 0, (size_t)4 * N * 4, stream);

  // qkT[b][i][o] = fp8((sum_c xnT[b][i][c]*wq[o][c] + b_qkv[o]) * scale)
  gemm_nt<4><<<dim3(8, 32, 4), 256, 0, stream>>>(
      xnT, wq_bf, 512, 512, 512, b_qkv, nullptr, scale,
      nullptr, qkT, 1024, NC, 0, (size_t)N * 1024);
  // vbf[b][c][j] = fp8(sum_k wq[1024+c][k]*xnT[b][j][k] + b_qkv[1024+c])
  gemm_nt<5><<<dim3(32, 4, 4), 256, 0, stream>>>(
      wq_bf + (size_t)1024 * 512, xnT, 512, 512, 512, b_qkv + 1024, nullptr,
      0.f, nullptr, vbf, 4096, 0, NC, (size_t)512 * 4096);
  // E[b][i][j] = fp8(exp(S)), rowsum[b][i] += partials (128^2, swizzled,
  // 3-stage counted-vmcnt)
  gemm_nt8<7, 1><<<dim3(32, 32, 4), 256, 0, stream>>>(
      qkT, qkT + 512, 1024, 1024, 512, nullptr, rowsum,
      E, 4096, (size_t)N * 1024, (size_t)N * 1024, (size_t)N * N);
  // ao[b][i][c] = bf16((sum_j E*v) * rcp(rowsum[b][i]))  (128x64 tiles,
  // 4 blocks/CU)
  gemm_pv<<<dim3(32, 8, 4), 256, 0, stream>>>(
      E, vbf, rowsum, ao, (size_t)N * N, (size_t)512 * 4096, NC);
  // out[b][o][n] = sum_c wp[o][c]*ao[b][n][c] + b_proj[o] + x[b][o][n]
  gemm_nt<3><<<dim3(32, 4, 4), 256, 0, stream>>>(
      wp_bf, ao, 512, 512, 512, b_proj, x, 0.f,
      out, nullptr, 4096, 0, NC, NC);
}

// Round 6
// 403.731 us; speedup vs baseline: 1.0608x; 1.0345x over previous
//
#include <hip/hip_runtime.h>
#include <hip/hip_fp8.h>
#include <stdint.h>

typedef unsigned short u16;
typedef unsigned char u8;
typedef __bf16 bf16x8 __attribute__((ext_vector_type(8)));
typedef float f32x4 __attribute__((ext_vector_type(4)));

__device__ __forceinline__ u16 f2bf(float f) {
  union { float f; unsigned u; } v; v.f = f;
  return (u16)((v.u + 0x7FFFu + ((v.u >> 16) & 1u)) >> 16);
}
__device__ __forceinline__ u8 f2f8(float f) {
  __hip_fp8_e4m3 h(f);
  return (u8)h.__x;
}

// async 16B global -> LDS (wave-uniform LDS base; HW writes base + lane*16)
__device__ __forceinline__ void gld_lds16(const void* g, void* l) {
  uint32_t lo = (uint32_t)(uintptr_t)l;
  lo = __builtin_amdgcn_readfirstlane(lo);
  auto* lp = (__attribute__((address_space(3))) uint32_t*)(uintptr_t)lo;
  auto* gp = (const __attribute__((address_space(1))) uint32_t*)(uintptr_t)g;
  __builtin_amdgcn_global_load_lds(gp, lp, 16, 0, 0);
}

// clobber-free barrier, fenced so no memory op crosses at schedule time.
__device__ __forceinline__ void bar() {
  __builtin_amdgcn_sched_barrier(0);
  __builtin_amdgcn_s_barrier();
  __builtin_amdgcn_sched_barrier(0);
}

// ---------------- weight fp32 -> bf16 ----------------
__global__ __launch_bounds__(256) void cvt_weights(
    const float* __restrict__ wq, const float* __restrict__ wp,
    u16* __restrict__ oq, u16* __restrict__ op) {
  int i = blockIdx.x * 256 + threadIdx.x;
  if (i < 1536 * 512) oq[i] = f2bf(wq[i]);
  if (i < 512 * 512)  op[i] = f2bf(wp[i]);
}

// ---------------- group norm stats ----------------
__global__ __launch_bounds__(256) void gn_stats(const float* __restrict__ x,
                                                float* __restrict__ stats) {
  int bg = blockIdx.x;  // 0..127
  const float* p = x + (size_t)bg * 65536;
  float s = 0.f, sq = 0.f;
  for (int i = threadIdx.x * 4; i < 65536; i += 1024) {
    float4 v = *(const float4*)(p + i);
    s += v.x + v.y + v.z + v.w;
    sq += v.x * v.x + v.y * v.y + v.z * v.z + v.w * v.w;
  }
  int lane = threadIdx.x & 63, w = threadIdx.x >> 6;
  for (int off = 32; off; off >>= 1) {
    s += __shfl_down(s, off);
    sq += __shfl_down(sq, off);
  }
  __shared__ float ls[4], lq[4];
  if (lane == 0) { ls[w] = s; lq[w] = sq; }
  __syncthreads();
  if (threadIdx.x == 0) {
    float S = ls[0] + ls[1] + ls[2] + ls[3];
    float Q = lq[0] + lq[1] + lq[2] + lq[3];
    float mean = S * (1.f / 65536.f);
    float var = Q * (1.f / 65536.f) - mean * mean;
    stats[bg * 2] = mean;
    stats[bg * 2 + 1] = rsqrtf(var + 1e-6f);
  }
}

// ---------------- group norm + transpose: x[b][c][n] -> xnT[b][n][c] bf16 ----
__global__ __launch_bounds__(256) void gn_norm_t(const float* __restrict__ x,
    const float* __restrict__ stats, const float* __restrict__ gamma,
    const float* __restrict__ beta, u16* __restrict__ xnT) {
  __shared__ u16 tile[64][72];
  int b = blockIdx.z;
  int c0 = blockIdx.y * 64, n0 = blockIdx.x * 64;
  int t = threadIdx.x;
  int cl = t >> 2, ng = (t & 3) * 16;
  int c = c0 + cl;
  float mean = stats[(b * 32 + (c >> 4)) * 2];
  float rstd = stats[(b * 32 + (c >> 4)) * 2 + 1];
  float a = gamma[c] * rstd;
  float b2 = beta[c] - mean * a;
  const float* src = x + ((size_t)b * 512 + c) * 4096 + n0 + ng;
  u16 e[16];
  #pragma unroll
  for (int q = 0; q < 4; ++q) {
    float4 v = *(const float4*)(src + q * 4);
    e[q * 4 + 0] = f2bf(v.x * a + b2);
    e[q * 4 + 1] = f2bf(v.y * a + b2);
    e[q * 4 + 2] = f2bf(v.z * a + b2);
    e[q * 4 + 3] = f2bf(v.w * a + b2);
  }
  #pragma unroll
  for (int j = 0; j < 16; ++j) tile[ng + j][cl] = e[j];
  __syncthreads();
  int nl = t >> 2, cg = (t & 3) * 16;
  uint4 w0 = *(const uint4*)&tile[nl][cg];
  uint4 w1 = *(const uint4*)&tile[nl][cg + 8];
  u16* dst = xnT + ((size_t)b * 4096 + n0 + nl) * 512 + c0 + cg;
  *(uint4*)dst = w0;
  *(uint4*)(dst + 8) = w1;
}

// ------------- bf16 NT GEMM: C[m][n] = sum_k A[m*lda+k]*B[n*ldb+k] --------
// 128x128 tile, BK=32, dbuf LDS + global_load_lds.
// EPI: 3 = fp32 out + bias[m] + resid (proj)
//      4 = fp8 out, (acc+bias[n])*scale  (qk: m=spatial, n=channel)
//      5 = fp8 out, acc+bias[m]          (v:  m=channel, n=spatial)
template<int EPI>
__global__ __launch_bounds__(256) void gemm_nt(
    const u16* __restrict__ A, const u16* __restrict__ B,
    int lda, int ldb, int K,
    const float* __restrict__ bias, const float* __restrict__ resid,
    float scale, float* __restrict__ outF, void* __restrict__ outBv, int ldo,
    size_t azs, size_t bzs, size_t ozs) {
  __shared__ __align__(16) u16 smem[16384];
  const size_t z = blockIdx.z;
  A += z * azs; B += z * bzs;
  const int t = threadIdx.x;
  const int wave = t >> 6, lane = t & 63;
  const int wm = wave >> 1, wn = wave & 1;
  const int quad = lane >> 4, li = lane & 15;
  const int m0 = blockIdx.y * 128, n0 = blockIdx.x * 128;

  const int srow = lane >> 2;
  const int scol = (lane & 3) * 8;
  const u16* gA[2];
  const u16* gB[2];
  int ldsOff[2];
  #pragma unroll
  for (int r = 0; r < 2; ++r) {
    int rb = wave + 4 * r;
    gA[r] = A + (size_t)(m0 + rb * 16 + srow) * lda + scol;
    gB[r] = B + (size_t)(n0 + rb * 16 + srow) * ldb + scol;
    ldsOff[r] = rb * 512;
  }

  f32x4 zero = {0.f, 0.f, 0.f, 0.f};
  f32x4 acc[4][4];
  #pragma unroll
  for (int i = 0; i < 4; ++i)
    #pragma unroll
    for (int j = 0; j < 4; ++j) acc[i][j] = zero;

  #pragma unroll
  for (int r = 0; r < 2; ++r) {
    gld_lds16(gA[r], &smem[ldsOff[r]]);
    gld_lds16(gB[r], &smem[8192 + ldsOff[r]]);
  }
  __syncthreads();

  for (int kt = 0; kt < K; kt += 32) {
    const int s = (kt >> 5) & 1;
    if (kt + 32 < K) {
      const int ns = s ^ 1;
      #pragma unroll
      for (int r = 0; r < 2; ++r) {
        gld_lds16(gA[r] + kt + 32, &smem[ns * 4096 + ldsOff[r]]);
        gld_lds16(gB[r] + kt + 32, &smem[8192 + ns * 4096 + ldsOff[r]]);
      }
    }
    bf16x8 af[4], bf[4];
    #pragma unroll
    for (int i = 0; i < 4; ++i) {
      af[i] = *(const bf16x8*)&smem[s * 4096 +
               (wm * 64 + i * 16 + li) * 32 + quad * 8];
      bf[i] = *(const bf16x8*)&smem[8192 + s * 4096 +
               (wn * 64 + i * 16 + li) * 32 + quad * 8];
    }
    #pragma unroll
    for (int i = 0; i < 4; ++i)
      #pragma unroll
      for (int j = 0; j < 4; ++j)
        acc[i][j] = __builtin_amdgcn_mfma_f32_16x16x32_bf16(
            af[i], bf[j], acc[i][j], 0, 0, 0);
    __syncthreads();
  }

  if (EPI == 3) {
    outF += z * ozs; resid += z * ozs;
    #pragma unroll
    for (int i = 0; i < 4; ++i)
      #pragma unroll
      for (int j = 0; j < 4; ++j) {
        int mB = m0 + wm * 64 + i * 16 + quad * 4;
        int n = n0 + wn * 64 + j * 16 + li;
        #pragma unroll
        for (int r = 0; r < 4; ++r) {
          int m = mB + r;
          float v = acc[i][j][r] + bias[m] + resid[(size_t)m * ldo + n];
          outF[(size_t)m * ldo + n] = v;
        }
      }
    return;
  }

  // fp8 outputs (EPI 4/5): bounce through LDS, coalesced stores
  u8* out8 = (u8*)outBv + z * ozs;
  u8* bnc = (u8*)smem;
  #pragma unroll
  for (int i = 0; i < 4; ++i) {
    int lm = wm * 64 + i * 16 + quad * 4;
    #pragma unroll
    for (int j = 0; j < 4; ++j) {
      int ln = wn * 64 + j * 16 + li;
      #pragma unroll
      for (int r = 0; r < 4; ++r) {
        float v = acc[i][j][r];
        u8 o;
        if (EPI == 4) o = f2f8((v + bias[n0 + ln]) * scale);
        else          o = f2f8(v + bias[m0 + lm + r]);
        bnc[(lm + r) * 144 + ln] = o;
      }
    }
  }
  __syncthreads();
  {
    int row = t >> 1, half = t & 1;
    const u8* src = &bnc[row * 144 + half * 64];
    u8* dst = out8 + (size_t)(m0 + row) * ldo + n0 + half * 64;
    #pragma unroll
    for (int cc = 0; cc < 4; ++cc)
      *(uint4*)(dst + cc * 16) = *(const uint4*)(src + cc * 16);
  }
}

// ------------- fp8 NT GEMM: C[m][n] = sum_k A[m*lda+k]*B[n*ldb+k] ---------
// 128x128 tile, BK=32/stage, FIVE-stage LDS pipeline, prefetch distance 4:
// the tile consumed at step t was issued 4 steps (~800-1600 cyc) earlier,
// covering L2/HBM latency (~200-900 cyc).  Distance 2 (round 2/3) still
// stalled every step — counted vmcnt alone is not enough, distance is.
// Steady-state wait vmcnt(6) (4 tiles x 2 loads in flight, oldest done);
// tail de-escalates 4/2/0.  Clobber-free waitcnt + builtin s_barrier.
// Frag reads swizzle-mapped (2-way max) via pre-swizzled GLOBAL source.
// EPI: 6 = bf16 out, acc * rcp(rowsum[m])  (PV)
//      7 = fp8 out exp(acc) (clamped 448), atomicAdd row-sums into outF
template<int EPI, int SWZ>
__global__ __launch_bounds__(256) void gemm_nt8(
    const u8* __restrict__ A, const u8* __restrict__ B,
    int lda, int ldb, int K,
    const float* __restrict__ rsum, float* __restrict__ outF,
    void* __restrict__ outBv, int ldo,
    size_t azs, size_t bzs, size_t ozs) {
  // stages (bytes): A s*4096 in [0,20480), B 20480+s*4096 in [20480,40960)
  // epilogue overlays: EPI7 u8 128x144 = 18432; EPI6 u16 128x136 = 34816
  __shared__ __align__(16) u8 smem[40960];
  const size_t z = blockIdx.z;
  A += z * azs; B += z * bzs;
  int bx = blockIdx.x, by = blockIdx.y;
  if (SWZ) {  // 16x16 super-tiles over a 32x32 grid
    int lin = by * 32 + bx;
    int tt = lin >> 8, w = lin & 255;
    by = (tt >> 1) * 16 + (w >> 4);
    bx = (tt & 1) * 16 + (w & 15);
  }
  const int t = threadIdx.x;
  const int wave = t >> 6, lane = t & 63;
  const int wm = wave >> 1, wn = wave & 1;
  const int quad = lane >> 4, li = lane & 15;
  const int m0 = by * 128, n0 = bx * 128;

  // staging: pre-swizzled source.  u = l ^ ((l>>3)&7); row = u>>1, half = u&1.
  const int us = lane ^ ((lane >> 3) & 7);
  const int srow = (us >> 1) & 31;
  const int shalf = us & 1;
  const u8* gA = A + (size_t)(m0 + wave * 32 + srow) * lda + shalf * 16;
  const u8* gB = B + (size_t)(n0 + wave * 32 + srow) * ldb + shalf * 16;
  const int ldsOff = wave * 1024;

  // frag read offsets: p = (2*r5+h) ^ ((r5>>2)&7)
  const int h = quad >> 1, qlo = (quad & 1) * 8;
  int aoff[4], boff[4];
  #pragma unroll
  for (int i = 0; i < 4; ++i) {
    int r5 = (i & 1) * 16 + li;
    int p = (2 * r5 + h) ^ ((r5 >> 2) & 7);
    aoff[i] = (wm * 2 + (i >> 1)) * 1024 + p * 16 + qlo;
    boff[i] = (wn * 2 + (i >> 1)) * 1024 + p * 16 + qlo;
  }

  f32x4 zero = {0.f, 0.f, 0.f, 0.f};
  f32x4 acc[4][4];
  #pragma unroll
  for (int i = 0; i < 4; ++i)
    #pragma unroll
    for (int j = 0; j < 4; ++j) acc[i][j] = zero;

  // prologue: stage tiles kt=0,32,64,96 (8 loads); wait tile0 only (vmcnt(6))
  // (K >= 128 for all call sites: 512 and 4096.)
  #pragma unroll
  for (int p = 0; p < 4; ++p) {
    gld_lds16(gA + p * 32, &smem[p * 4096 + ldsOff]);
    gld_lds16(gB + p * 32, &smem[20480 + p * 4096 + ldsOff]);
  }
  __builtin_amdgcn_sched_barrier(0);
  asm volatile("s_waitcnt vmcnt(6)");
  bar();

  int s = 0;
  for (int kt = 0; kt < K; kt += 32) {
    if (kt + 128 < K) {
      const int ns = (s >= 1) ? s - 1 : 4;  // (s+4)%5
      gld_lds16(gA + kt + 128, &smem[ns * 4096 + ldsOff]);
      gld_lds16(gB + kt + 128, &smem[20480 + ns * 4096 + ldsOff]);
    }
    const int sb = s * 4096;
    long af[4], bf[4];
    #pragma unroll
    for (int i = 0; i < 4; ++i) {
      af[i] = *(const long*)&smem[sb + aoff[i]];
      bf[i] = *(const long*)&smem[20480 + sb + boff[i]];
    }
    #pragma unroll
    for (int i = 0; i < 4; ++i)
      #pragma unroll
      for (int j = 0; j < 4; ++j)
        acc[i][j] = __builtin_amdgcn_mfma_f32_16x16x32_fp8_fp8(
            af[i], bf[j], acc[i][j], 0, 0, 0);
    if (kt + 32 < K) {
      __builtin_amdgcn_sched_barrier(0);
      if      (kt + 128 < K) asm volatile("s_waitcnt vmcnt(6)");
      else if (kt + 96  < K) asm volatile("s_waitcnt vmcnt(4)");
      else if (kt + 64  < K) asm volatile("s_waitcnt vmcnt(2)");
      else                   asm volatile("s_waitcnt vmcnt(0)");
      bar();
    }
    s = (s == 4) ? 0 : s + 1;
  }
  __syncthreads();  // all waves done reading stages before bounce overlay

  if (EPI == 7) {
    float* rsF = outF + z * 4096;
    u8* outE = (u8*)outBv + z * ozs;
    #pragma unroll
    for (int i = 0; i < 4; ++i) {
      int lm = wm * 64 + i * 16 + quad * 4;
      float rs[4] = {0.f, 0.f, 0.f, 0.f};
      #pragma unroll
      for (int j = 0; j < 4; ++j) {
        int ln = wn * 64 + j * 16 + li;
        #pragma unroll
        for (int r = 0; r < 4; ++r) {
          float e = fminf(__expf(acc[i][j][r]), 448.f);
          smem[(lm + r) * 144 + ln] = f2f8(e);
          rs[r] += e;
        }
      }
      #pragma unroll
      for (int r = 0; r < 4; ++r) {
        rs[r] += __shfl_xor(rs[r], 1);
        rs[r] += __shfl_xor(rs[r], 2);
        rs[r] += __shfl_xor(rs[r], 4);
        rs[r] += __shfl_xor(rs[r], 8);
      }
      if (li == 0) {
        #pragma unroll
        for (int r = 0; r < 4; ++r) atomicAdd(&rsF[m0 + lm + r], rs[r]);
      }
    }
    __syncthreads();
    int row = t >> 1, half = t & 1;
    const u8* src = &smem[row * 144 + half * 64];
    u8* dst = outE + (size_t)(m0 + row) * ldo + n0 + half * 64;
    #pragma unroll
    for (int cc = 0; cc < 4; ++cc)
      *(uint4*)(dst + cc * 16) = *(const uint4*)(src + cc * 16);
  } else {  // EPI 6: PV
    const float* rsF = rsum + z * 4096;
    u16* outp = (u16*)outBv + z * ozs;
    u16* b16 = (u16*)smem;
    #pragma unroll
    for (int i = 0; i < 4; ++i) {
      int lm = wm * 64 + i * 16 + quad * 4;
      float rinv[4];
      #pragma unroll
      for (int r = 0; r < 4; ++r)
        rinv[r] = __builtin_amdgcn_rcpf(rsF[m0 + lm + r]);
      #pragma unroll
      for (int j = 0; j < 4; ++j) {
        int ln = wn * 64 + j * 16 + li;
        #pragma unroll
        for (int r = 0; r < 4; ++r)
          b16[(lm + r) * 136 + ln] = f2bf(acc[i][j][r] * rinv[r]);
      }
    }
    __syncthreads();
    int row = t >> 1, half = t & 1;
    const u16* src = &b16[row * 136 + half * 64];
    u16* dst = outp + (size_t)(m0 + row) * ldo + n0 + half * 64;
    #pragma unroll
    for (int cc = 0; cc < 8; ++cc)
      *(uint4*)(dst + cc * 8) = *(const uint4*)(src + cc * 8);
  }
}

extern "C" void kernel_launch(void* const* d_in, const int* in_sizes, int n_in,
                              void* d_out, int out_size, void* d_ws, size_t ws_size,
                              hipStream_t stream) {
  (void)in_sizes; (void)n_in; (void)out_size; (void)ws_size;
  const float* x      = (const float*)d_in[0];
  const float* gamma  = (const float*)d_in[1];
  const float* beta   = (const float*)d_in[2];
  const float* w_qkv  = (const float*)d_in[3];
  const float* b_qkv  = (const float*)d_in[4];
  const float* w_proj = (const float*)d_in[5];
  const float* b_proj = (const float*)d_in[6];
  float* out = (float*)d_out;

  const int C = 512, N = 4096;
  const size_t NC = (size_t)N * C;
  const float scale = 0.21022410381342863f;  // 512^-0.25

  char* ws = (char*)d_ws;
  size_t off = 0;
  auto alloc = [&](size_t bytes) -> char* {
    char* p = ws + off; off += (bytes + 255) & ~(size_t)255; return p;
  };
  u16*   wq_bf  = (u16*)alloc((size_t)1536 * 512 * 2);
  u16*   wp_bf  = (u16*)alloc((size_t)512 * 512 * 2);
  float* stats  = (float*)alloc(128 * 2 * 4);
  float* rowsum = (float*)alloc((size_t)4 * N * 4);
  u16*   xnT    = (u16*)alloc((size_t)4 * NC * 2);      // [b][n][c] bf16
  u8*    qkT    = (u8*)alloc((size_t)4 * N * 1024);     // [b][i][o] fp8, o<1024
  u8*    vbf    = (u8*)alloc((size_t)4 * 512 * 4096);   // [b][c][j] fp8
  u16*   ao     = (u16*)alloc((size_t)4 * NC * 2);      // [b][i][c] bf16
  u8*    E      = (u8*)alloc((size_t)4 * N * N);        // [b][i][j] fp8

  cvt_weights<<<3072, 256, 0, stream>>>(w_qkv, w_proj, wq_bf, wp_bf);
  gn_stats<<<128, 256, 0, stream>>>(x, stats);
  gn_norm_t<<<dim3(64, 8, 4), 256, 0, stream>>>(x, stats, gamma, beta, xnT);
  hipMemsetAsync(rowsum, 0, (size_t)4 * N * 4, stream);

  // qkT[b][i][o] = fp8((sum_c xnT[b][i][c]*wq[o][c] + b_qkv[o]) * scale)
  gemm_nt<4><<<dim3(8, 32, 4), 256, 0, stream>>>(
      xnT, wq_bf, 512, 512, 512, b_qkv, nullptr, scale,
      nullptr, qkT, 1024, NC, 0, (size_t)N * 1024);
  // vbf[b][c][j] = fp8(sum_k wq[1024+c][k]*xnT[b][j][k] + b_qkv[1024+c])
  gemm_nt<5><<<dim3(32, 4, 4), 256, 0, stream>>>(
      wq_bf + (size_t)1024 * 512, xnT, 512, 512, 512, b_qkv + 1024, nullptr,
      0.f, nullptr, vbf, 4096, 0, NC, (size_t)512 * 4096);
  // E[b][i][j] = fp8(exp(S)), rowsum[b][i] += partials (5-stage, distance-4)
  gemm_nt8<7, 1><<<dim3(32, 32, 4), 256, 0, stream>>>(
      qkT, qkT + 512, 1024, 1024, 512, nullptr, rowsum,
      E, 4096, (size_t)N * 1024, (size_t)N * 1024, (size_t)N * N);
  // ao[b][i][c] = bf16((sum_j E*v) * rcp(rowsum[b][i]))  (K=4096, 5-stage)
  gemm_nt8<6, 0><<<dim3(4, 32, 4), 256, 0, stream>>>(
      E, vbf, 4096, 4096, 4096, rowsum, nullptr,
      ao, 512, (size_t)N * N, (size_t)512 * 4096, NC);
  // out[b][o][n] = sum_c wp[o][c]*ao[b][n][c] + b_proj[o] + x[b][o][n]
  gemm_nt<3><<<dim3(32, 4, 4), 256, 0, stream>>>(
      wp_bf, ao, 512, 512, 512, b_proj, x, 0.f,
      out, nullptr, 4096, 0, NC, NC);
}

// Round 7
// 367.021 us; speedup vs baseline: 1.1669x; 1.1000x over previous
//
#include <hip/hip_runtime.h>
#include <hip/hip_fp8.h>
#include <stdint.h>

typedef unsigned short u16;
typedef unsigned char u8;
typedef __bf16 bf16x8 __attribute__((ext_vector_type(8)));
typedef float f32x4 __attribute__((ext_vector_type(4)));

__device__ __forceinline__ u16 f2bf(float f) {
  union { float f; unsigned u; } v; v.f = f;
  return (u16)((v.u + 0x7FFFu + ((v.u >> 16) & 1u)) >> 16);
}
__device__ __forceinline__ u8 f2f8(float f) {
  __hip_fp8_e4m3 h(f);
  return (u8)h.__x;
}

// async 16B global -> LDS (wave-uniform LDS base; HW writes base + lane*16)
__device__ __forceinline__ void gld_lds16(const void* g, void* l) {
  uint32_t lo = (uint32_t)(uintptr_t)l;
  lo = __builtin_amdgcn_readfirstlane(lo);
  auto* lp = (__attribute__((address_space(3))) uint32_t*)(uintptr_t)lo;
  auto* gp = (const __attribute__((address_space(1))) uint32_t*)(uintptr_t)g;
  __builtin_amdgcn_global_load_lds(gp, lp, 16, 0, 0);
}

// clobber-free barrier, fenced so no memory op crosses at schedule time.
__device__ __forceinline__ void bar() {
  __builtin_amdgcn_sched_barrier(0);
  __builtin_amdgcn_s_barrier();
  __builtin_amdgcn_sched_barrier(0);
}

// ---------------- weight fp32 -> bf16 ----------------
__global__ __launch_bounds__(256) void cvt_weights(
    const float* __restrict__ wq, const float* __restrict__ wp,
    u16* __restrict__ oq, u16* __restrict__ op) {
  int i = blockIdx.x * 256 + threadIdx.x;
  if (i < 1536 * 512) oq[i] = f2bf(wq[i]);
  if (i < 512 * 512)  op[i] = f2bf(wp[i]);
}

// ---------------- group norm stats ----------------
__global__ __launch_bounds__(256) void gn_stats(const float* __restrict__ x,
                                                float* __restrict__ stats) {
  int bg = blockIdx.x;  // 0..127
  const float* p = x + (size_t)bg * 65536;
  float s = 0.f, sq = 0.f;
  for (int i = threadIdx.x * 4; i < 65536; i += 1024) {
    float4 v = *(const float4*)(p + i);
    s += v.x + v.y + v.z + v.w;
    sq += v.x * v.x + v.y * v.y + v.z * v.z + v.w * v.w;
  }
  int lane = threadIdx.x & 63, w = threadIdx.x >> 6;
  for (int off = 32; off; off >>= 1) {
    s += __shfl_down(s, off);
    sq += __shfl_down(sq, off);
  }
  __shared__ float ls[4], lq[4];
  if (lane == 0) { ls[w] = s; lq[w] = sq; }
  __syncthreads();
  if (threadIdx.x == 0) {
    float S = ls[0] + ls[1] + ls[2] + ls[3];
    float Q = lq[0] + lq[1] + lq[2] + lq[3];
    float mean = S * (1.f / 65536.f);
    float var = Q * (1.f / 65536.f) - mean * mean;
    stats[bg * 2] = mean;
    stats[bg * 2 + 1] = rsqrtf(var + 1e-6f);
  }
}

// ---------------- group norm + transpose: x[b][c][n] -> xnT[b][n][c] bf16 ----
__global__ __launch_bounds__(256) void gn_norm_t(const float* __restrict__ x,
    const float* __restrict__ stats, const float* __restrict__ gamma,
    const float* __restrict__ beta, u16* __restrict__ xnT) {
  __shared__ u16 tile[64][72];
  int b = blockIdx.z;
  int c0 = blockIdx.y * 64, n0 = blockIdx.x * 64;
  int t = threadIdx.x;
  int cl = t >> 2, ng = (t & 3) * 16;
  int c = c0 + cl;
  float mean = stats[(b * 32 + (c >> 4)) * 2];
  float rstd = stats[(b * 32 + (c >> 4)) * 2 + 1];
  float a = gamma[c] * rstd;
  float b2 = beta[c] - mean * a;
  const float* src = x + ((size_t)b * 512 + c) * 4096 + n0 + ng;
  u16 e[16];
  #pragma unroll
  for (int q = 0; q < 4; ++q) {
    float4 v = *(const float4*)(src + q * 4);
    e[q * 4 + 0] = f2bf(v.x * a + b2);
    e[q * 4 + 1] = f2bf(v.y * a + b2);
    e[q * 4 + 2] = f2bf(v.z * a + b2);
    e[q * 4 + 3] = f2bf(v.w * a + b2);
  }
  #pragma unroll
  for (int j = 0; j < 16; ++j) tile[ng + j][cl] = e[j];
  __syncthreads();
  int nl = t >> 2, cg = (t & 3) * 16;
  uint4 w0 = *(const uint4*)&tile[nl][cg];
  uint4 w1 = *(const uint4*)&tile[nl][cg + 8];
  u16* dst = xnT + ((size_t)b * 4096 + n0 + nl) * 512 + c0 + cg;
  *(uint4*)dst = w0;
  *(uint4*)(dst + 8) = w1;
}

// ------------- bf16 NT GEMM: C[m][n] = sum_k A[m*lda+k]*B[n*ldb+k] --------
// 128x128 tile, BK=32, dbuf LDS + global_load_lds.
// EPI: 3 = fp32 out + bias[m] + resid (proj)
//      4 = fp8 out, (acc+bias[n])*scale  (qk: m=spatial, n=channel)
//      5 = fp8 out, acc+bias[m]          (v:  m=channel, n=spatial)
template<int EPI>
__global__ __launch_bounds__(256) void gemm_nt(
    const u16* __restrict__ A, const u16* __restrict__ B,
    int lda, int ldb, int K,
    const float* __restrict__ bias, const float* __restrict__ resid,
    float scale, float* __restrict__ outF, void* __restrict__ outBv, int ldo,
    size_t azs, size_t bzs, size_t ozs) {
  __shared__ __align__(16) u16 smem[16384];
  const size_t z = blockIdx.z;
  A += z * azs; B += z * bzs;
  const int t = threadIdx.x;
  const int wave = t >> 6, lane = t & 63;
  const int wm = wave >> 1, wn = wave & 1;
  const int quad = lane >> 4, li = lane & 15;
  const int m0 = blockIdx.y * 128, n0 = blockIdx.x * 128;

  const int srow = lane >> 2;
  const int scol = (lane & 3) * 8;
  const u16* gA[2];
  const u16* gB[2];
  int ldsOff[2];
  #pragma unroll
  for (int r = 0; r < 2; ++r) {
    int rb = wave + 4 * r;
    gA[r] = A + (size_t)(m0 + rb * 16 + srow) * lda + scol;
    gB[r] = B + (size_t)(n0 + rb * 16 + srow) * ldb + scol;
    ldsOff[r] = rb * 512;
  }

  f32x4 zero = {0.f, 0.f, 0.f, 0.f};
  f32x4 acc[4][4];
  #pragma unroll
  for (int i = 0; i < 4; ++i)
    #pragma unroll
    for (int j = 0; j < 4; ++j) acc[i][j] = zero;

  #pragma unroll
  for (int r = 0; r < 2; ++r) {
    gld_lds16(gA[r], &smem[ldsOff[r]]);
    gld_lds16(gB[r], &smem[8192 + ldsOff[r]]);
  }
  __syncthreads();

  for (int kt = 0; kt < K; kt += 32) {
    const int s = (kt >> 5) & 1;
    if (kt + 32 < K) {
      const int ns = s ^ 1;
      #pragma unroll
      for (int r = 0; r < 2; ++r) {
        gld_lds16(gA[r] + kt + 32, &smem[ns * 4096 + ldsOff[r]]);
        gld_lds16(gB[r] + kt + 32, &smem[8192 + ns * 4096 + ldsOff[r]]);
      }
    }
    bf16x8 af[4], bf[4];
    #pragma unroll
    for (int i = 0; i < 4; ++i) {
      af[i] = *(const bf16x8*)&smem[s * 4096 +
               (wm * 64 + i * 16 + li) * 32 + quad * 8];
      bf[i] = *(const bf16x8*)&smem[8192 + s * 4096 +
               (wn * 64 + i * 16 + li) * 32 + quad * 8];
    }
    #pragma unroll
    for (int i = 0; i < 4; ++i)
      #pragma unroll
      for (int j = 0; j < 4; ++j)
        acc[i][j] = __builtin_amdgcn_mfma_f32_16x16x32_bf16(
            af[i], bf[j], acc[i][j], 0, 0, 0);
    __syncthreads();
  }

  if (EPI == 3) {
    outF += z * ozs; resid += z * ozs;
    #pragma unroll
    for (int i = 0; i < 4; ++i)
      #pragma unroll
      for (int j = 0; j < 4; ++j) {
        int mB = m0 + wm * 64 + i * 16 + quad * 4;
        int n = n0 + wn * 64 + j * 16 + li;
        #pragma unroll
        for (int r = 0; r < 4; ++r) {
          int m = mB + r;
          float v = acc[i][j][r] + bias[m] + resid[(size_t)m * ldo + n];
          outF[(size_t)m * ldo + n] = v;
        }
      }
    return;
  }

  // fp8 outputs (EPI 4/5): bounce through LDS, coalesced stores
  u8* out8 = (u8*)outBv + z * ozs;
  u8* bnc = (u8*)smem;
  #pragma unroll
  for (int i = 0; i < 4; ++i) {
    int lm = wm * 64 + i * 16 + quad * 4;
    #pragma unroll
    for (int j = 0; j < 4; ++j) {
      int ln = wn * 64 + j * 16 + li;
      #pragma unroll
      for (int r = 0; r < 4; ++r) {
        float v = acc[i][j][r];
        u8 o;
        if (EPI == 4) o = f2f8((v + bias[n0 + ln]) * scale);
        else          o = f2f8(v + bias[m0 + lm + r]);
        bnc[(lm + r) * 144 + ln] = o;
      }
    }
  }
  __syncthreads();
  {
    int row = t >> 1, half = t & 1;
    const u8* src = &bnc[row * 144 + half * 64];
    u8* dst = out8 + (size_t)(m0 + row) * ldo + n0 + half * 64;
    #pragma unroll
    for (int cc = 0; cc < 4; ++cc)
      *(uint4*)(dst + cc * 16) = *(const uint4*)(src + cc * 16);
  }
}

// ------------- fp8 NT GEMM: C[m][n] = sum_k A[m*lda+k]*B[n*ldb+k] ---------
// 128x128 tile, BK=64 per step (two 32-col panels side by side), 3-stage
// LDS (3 x 16KB = 48KB -> 3 blocks/CU), prefetch distance 2 steps,
// counted clobber-free vmcnt(4) at boundaries.  Six rounds of A/B pinned
// the cost as ~fixed per barrier-step (independent of conflicts, wait
// depth, occupancy) — so halve the step count and double MFMA per step:
// 32 MFMA + 16 ds_read_b64 per wave per step, 8 steps (QK) / 64 (PV).
// Frag reads swizzle-mapped (2-way max) via pre-swizzled GLOBAL source;
// panel-internal layout identical to the BK=32 scheme.  FP accumulation
// order preserved (panel0 then panel1, k ascending).
// EPI: 6 = bf16 out, acc * rcp(rowsum[m])  (PV)
//      7 = fp8 out exp(acc) (clamped 448), atomicAdd row-sums into outF
template<int EPI, int SWZ>
__global__ __launch_bounds__(256) void gemm_nt8(
    const u8* __restrict__ A, const u8* __restrict__ B,
    int lda, int ldb, int K,
    const float* __restrict__ rsum, float* __restrict__ outF,
    void* __restrict__ outBv, int ldo,
    size_t azs, size_t bzs, size_t ozs) {
  // stages (bytes): A s*8192 in [0,24576), B 24576+s*8192 in [24576,49152)
  // within a stage: panel g (cols g*32..) at g*4096, region w at w*1024
  // epilogue overlays: EPI7 u8 128x144 = 18432; EPI6 u16 128x136 = 34816
  __shared__ __align__(16) u8 smem[49152];
  const size_t z = blockIdx.z;
  A += z * azs; B += z * bzs;
  int bx = blockIdx.x, by = blockIdx.y;
  if (SWZ) {  // 16x16 super-tiles over a 32x32 grid
    int lin = by * 32 + bx;
    int tt = lin >> 8, w = lin & 255;
    by = (tt >> 1) * 16 + (w >> 4);
    bx = (tt & 1) * 16 + (w & 15);
  }
  const int t = threadIdx.x;
  const int wave = t >> 6, lane = t & 63;
  const int wm = wave >> 1, wn = wave & 1;
  const int quad = lane >> 4, li = lane & 15;
  const int m0 = by * 128, n0 = bx * 128;

  // staging: pre-swizzled source.  u = l ^ ((l>>3)&7); row = u>>1, half = u&1.
  const int us = lane ^ ((lane >> 3) & 7);
  const int srow = (us >> 1) & 31;
  const int shalf = us & 1;
  const u8* gA = A + (size_t)(m0 + wave * 32 + srow) * lda + shalf * 16;
  const u8* gB = B + (size_t)(n0 + wave * 32 + srow) * ldb + shalf * 16;
  const int ldsOff = wave * 1024;

  // frag read offsets within a panel: p = (2*r5+h) ^ ((r5>>2)&7)
  const int h = quad >> 1, qlo = (quad & 1) * 8;
  int aoff[4], boff[4];
  #pragma unroll
  for (int i = 0; i < 4; ++i) {
    int r5 = (i & 1) * 16 + li;
    int p = (2 * r5 + h) ^ ((r5 >> 2) & 7);
    aoff[i] = (wm * 2 + (i >> 1)) * 1024 + p * 16 + qlo;
    boff[i] = (wn * 2 + (i >> 1)) * 1024 + p * 16 + qlo;
  }

  f32x4 zero = {0.f, 0.f, 0.f, 0.f};
  f32x4 acc[4][4];
  #pragma unroll
  for (int i = 0; i < 4; ++i)
    #pragma unroll
    for (int j = 0; j < 4; ++j) acc[i][j] = zero;

  // prologue: stage steps 0,1 (kt=0,64); 8 loads; wait step0 (vmcnt(4))
  #pragma unroll
  for (int p = 0; p < 2; ++p) {
    gld_lds16(gA + p * 64,      &smem[p * 8192 + ldsOff]);
    gld_lds16(gA + p * 64 + 32, &smem[p * 8192 + 4096 + ldsOff]);
    gld_lds16(gB + p * 64,      &smem[24576 + p * 8192 + ldsOff]);
    gld_lds16(gB + p * 64 + 32, &smem[24576 + p * 8192 + 4096 + ldsOff]);
  }
  __builtin_amdgcn_sched_barrier(0);
  asm volatile("s_waitcnt vmcnt(4)");
  bar();

  int s = 0;
  for (int kt = 0; kt < K; kt += 64) {
    if (kt + 128 < K) {
      const int ns = (s == 0) ? 2 : s - 1;  // (s+2)%3
      gld_lds16(gA + kt + 128,      &smem[ns * 8192 + ldsOff]);
      gld_lds16(gA + kt + 128 + 32, &smem[ns * 8192 + 4096 + ldsOff]);
      gld_lds16(gB + kt + 128,      &smem[24576 + ns * 8192 + ldsOff]);
      gld_lds16(gB + kt + 128 + 32, &smem[24576 + ns * 8192 + 4096 + ldsOff]);
    }
    const int sb = s * 8192;
    long af[4][2], bf[4][2];
    #pragma unroll
    for (int i = 0; i < 4; ++i) {
      #pragma unroll
      for (int g = 0; g < 2; ++g) {
        af[i][g] = *(const long*)&smem[sb + g * 4096 + aoff[i]];
        bf[i][g] = *(const long*)&smem[24576 + sb + g * 4096 + boff[i]];
      }
    }
    #pragma unroll
    for (int i = 0; i < 4; ++i)
      #pragma unroll
      for (int j = 0; j < 4; ++j) {
        acc[i][j] = __builtin_amdgcn_mfma_f32_16x16x32_fp8_fp8(
            af[i][0], bf[j][0], acc[i][j], 0, 0, 0);
        acc[i][j] = __builtin_amdgcn_mfma_f32_16x16x32_fp8_fp8(
            af[i][1], bf[j][1], acc[i][j], 0, 0, 0);
      }
    if (kt + 64 < K) {
      __builtin_amdgcn_sched_barrier(0);
      if (kt + 128 < K) asm volatile("s_waitcnt vmcnt(4)");
      else              asm volatile("s_waitcnt vmcnt(0)");
      bar();
    }
    s = (s == 2) ? 0 : s + 1;
  }
  __syncthreads();  // all waves done reading stages before bounce overlay

  if (EPI == 7) {
    float* rsF = outF + z * 4096;
    u8* outE = (u8*)outBv + z * ozs;
    #pragma unroll
    for (int i = 0; i < 4; ++i) {
      int lm = wm * 64 + i * 16 + quad * 4;
      float rs[4] = {0.f, 0.f, 0.f, 0.f};
      #pragma unroll
      for (int j = 0; j < 4; ++j) {
        int ln = wn * 64 + j * 16 + li;
        #pragma unroll
        for (int r = 0; r < 4; ++r) {
          float e = fminf(__expf(acc[i][j][r]), 448.f);
          smem[(lm + r) * 144 + ln] = f2f8(e);
          rs[r] += e;
        }
      }
      #pragma unroll
      for (int r = 0; r < 4; ++r) {
        rs[r] += __shfl_xor(rs[r], 1);
        rs[r] += __shfl_xor(rs[r], 2);
        rs[r] += __shfl_xor(rs[r], 4);
        rs[r] += __shfl_xor(rs[r], 8);
      }
      if (li == 0) {
        #pragma unroll
        for (int r = 0; r < 4; ++r) atomicAdd(&rsF[m0 + lm + r], rs[r]);
      }
    }
    __syncthreads();
    int row = t >> 1, half = t & 1;
    const u8* src = &smem[row * 144 + half * 64];
    u8* dst = outE + (size_t)(m0 + row) * ldo + n0 + half * 64;
    #pragma unroll
    for (int cc = 0; cc < 4; ++cc)
      *(uint4*)(dst + cc * 16) = *(const uint4*)(src + cc * 16);
  } else {  // EPI 6: PV
    const float* rsF = rsum + z * 4096;
    u16* outp = (u16*)outBv + z * ozs;
    u16* b16 = (u16*)smem;
    #pragma unroll
    for (int i = 0; i < 4; ++i) {
      int lm = wm * 64 + i * 16 + quad * 4;
      float rinv[4];
      #pragma unroll
      for (int r = 0; r < 4; ++r)
        rinv[r] = __builtin_amdgcn_rcpf(rsF[m0 + lm + r]);
      #pragma unroll
      for (int j = 0; j < 4; ++j) {
        int ln = wn * 64 + j * 16 + li;
        #pragma unroll
        for (int r = 0; r < 4; ++r)
          b16[(lm + r) * 136 + ln] = f2bf(acc[i][j][r] * rinv[r]);
      }
    }
    __syncthreads();
    int row = t >> 1, half = t & 1;
    const u16* src = &b16[row * 136 + half * 64];
    u16* dst = outp + (size_t)(m0 + row) * ldo + n0 + half * 64;
    #pragma unroll
    for (int cc = 0; cc < 8; ++cc)
      *(uint4*)(dst + cc * 8) = *(const uint4*)(src + cc * 8);
  }
}

extern "C" void kernel_launch(void* const* d_in, const int* in_sizes, int n_in,
                              void* d_out, int out_size, void* d_ws, size_t ws_size,
                              hipStream_t stream) {
  (void)in_sizes; (void)n_in; (void)out_size; (void)ws_size;
  const float* x      = (const float*)d_in[0];
  const float* gamma  = (const float*)d_in[1];
  const float* beta   = (const float*)d_in[2];
  const float* w_qkv  = (const float*)d_in[3];
  const float* b_qkv  = (const float*)d_in[4];
  const float* w_proj = (const float*)d_in[5];
  const float* b_proj = (const float*)d_in[6];
  float* out = (float*)d_out;

  const int C = 512, N = 4096;
  const size_t NC = (size_t)N * C;
  const float scale = 0.21022410381342863f;  // 512^-0.25

  char* ws = (char*)d_ws;
  size_t off = 0;
  auto alloc = [&](size_t bytes) -> char* {
    char* p = ws + off; off += (bytes + 255) & ~(size_t)255; return p;
  };
  u16*   wq_bf  = (u16*)alloc((size_t)1536 * 512 * 2);
  u16*   wp_bf  = (u16*)alloc((size_t)512 * 512 * 2);
  float* stats  = (float*)alloc(128 * 2 * 4);
  float* rowsum = (float*)alloc((size_t)4 * N * 4);
  u16*   xnT    = (u16*)alloc((size_t)4 * NC * 2);      // [b][n][c] bf16
  u8*    qkT    = (u8*)alloc((size_t)4 * N * 1024);     // [b][i][o] fp8, o<1024
  u8*    vbf    = (u8*)alloc((size_t)4 * 512 * 4096);   // [b][c][j] fp8
  u16*   ao     = (u16*)alloc((size_t)4 * NC * 2);      // [b][i][c] bf16
  u8*    E      = (u8*)alloc((size_t)4 * N * N);        // [b][i][j] fp8

  cvt_weights<<<3072, 256, 0, stream>>>(w_qkv, w_proj, wq_bf, wp_bf);
  gn_stats<<<128, 256, 0, stream>>>(x, stats);
  gn_norm_t<<<dim3(64, 8, 4), 256, 0, stream>>>(x, stats, gamma, beta, xnT);
  hipMemsetAsync(rowsum, 0, (size_t)4 * N * 4, stream);

  // qkT[b][i][o] = fp8((sum_c xnT[b][i][c]*wq[o][c] + b_qkv[o]) * scale)
  gemm_nt<4><<<dim3(8, 32, 4), 256, 0, stream>>>(
      xnT, wq_bf, 512, 512, 512, b_qkv, nullptr, scale,
      nullptr, qkT, 1024, NC, 0, (size_t)N * 1024);
  // vbf[b][c][j] = fp8(sum_k wq[1024+c][k]*xnT[b][j][k] + b_qkv[1024+c])
  gemm_nt<5><<<dim3(32, 4, 4), 256, 0, stream>>>(
      wq_bf + (size_t)1024 * 512, xnT, 512, 512, 512, b_qkv + 1024, nullptr,
      0.f, nullptr, vbf, 4096, 0, NC, (size_t)512 * 4096);
  // E[b][i][j] = fp8(exp(S)), rowsum[b][i] += partials (BK=64, 8 steps)
  gemm_nt8<7, 1><<<dim3(32, 32, 4), 256, 0, stream>>>(
      qkT, qkT + 512, 1024, 1024, 512, nullptr, rowsum,
      E, 4096, (size_t)N * 1024, (size_t)N * 1024, (size_t)N * N);
  // ao[b][i][c] = bf16((sum_j E*v) * rcp(rowsum[b][i]))  (BK=64, 64 steps)
  gemm_nt8<6, 0><<<dim3(4, 32, 4), 256, 0, stream>>>(
      E, vbf, 4096, 4096, 4096, rowsum, nullptr,
      ao, 512, (size_t)N * N, (size_t)512 * 4096, NC);
  // out[b][o][n] = sum_c wp[o][c]*ao[b][n][c] + b_proj[o] + x[b][o][n]
  gemm_nt<3><<<dim3(32, 4, 4), 256, 0, stream>>>(
      wp_bf, ao, 512, 512, 512, b_proj, x, 0.f,
      out, nullptr, 4096, 0, NC, NC);
}